// Round 4
// baseline (514.347 us; speedup 1.0000x reference)
//
#include <hip/hip_runtime.h>
#include <cstdint>
#include <cstddef>

#define B_ 16
#define C_ 256
#define T_ 128
#define V_ 64
#define K_ 8
#define O_ 256
#define TN 8192      /* T_*V_ */
#define NBT 131072   /* B_*T_*V_ : BN sample count */
#define NSL 32       /* stats slices (atomic contention spreader) */

typedef unsigned short ushort_t;
typedef __attribute__((ext_vector_type(8))) short short8;
typedef __attribute__((ext_vector_type(4))) float f32x4;

/* ---- workspace layout (float offsets) ---- */
#define OFF_TP     0          /* [B][C][V] 262144; reused for w-images (bf16) after x1x2 */
#define OFF_X1     262144
#define OFF_X2     524288
#define OFF_STATS  786432     /* 4 arrays x [NSL][256] = 32768 */
#define OFF_SSC    819200     /* stem scale/shift 512 */
#define OFF_HSC    819712
#define OFF_ADA    820224     /* [B][K][V][V] 524288 -> ends 1344512 */
#define OFF_Z      1344512    /* z bf16 [B][O][TN] : 33554432 ushort = 16777216 f32; u reuses it */
#define OFF_H2     34867200   /* h2 bf16 image 16777216 ushort */

__device__ inline ushort_t f2bf(float f) {
    unsigned u = __builtin_bit_cast(unsigned, f);
    unsigned r = (u + 0x7FFFu + ((u >> 16) & 1u)) >> 16;
    return (ushort_t)r;
}
__device__ inline unsigned pack2(float a, float b) {
    return (unsigned)f2bf(a) | ((unsigned)f2bf(b) << 16);
}
__device__ inline float bf2f_lo(unsigned u) { return __builtin_bit_cast(float, u << 16); }
__device__ inline float bf2f_hi(unsigned u) { return __builtin_bit_cast(float, u & 0xFFFF0000u); }
__device__ inline void gload_lds16(const void* g, void* l) {
    __builtin_amdgcn_global_load_lds((const __attribute__((address_space(1))) unsigned int*)g,
                                     (__attribute__((address_space(3))) unsigned int*)l, 16, 0, 0);
}

/* x [b][c][t][v] fp32 -> bf16 frag image ((b*128+t)*8+cc)*2048 + q*512 + v*8 + cl
   (c = cc*32+q*8+cl); fused per-(b,c,v) mean over t.
   v4: each WAVE reads one c-row contiguously (8KB = 32t x 64v) -- fixes the HBM
   channel hotspot of v1/v2 (same-t bursts, 1.2 TB/s read ceiling). 512 threads. */
__global__ __launch_bounds__(512) void k_xpose2(const float* __restrict__ x,
                                                ushort_t* __restrict__ img,
                                                float* __restrict__ tp) {
    __shared__ float L[8 * 2048];   /* [c 8][t 32][v 64] */
    int tq = blockIdx.x;            /* 0..3 : t-range tq*32 .. +31 */
    int cg = blockIdx.y;            /* 0..7 : c-range cg*32 .. +31 */
    int b  = blockIdx.z;
    int tid  = threadIdx.x;
    int wv   = tid >> 6;            /* 0..7 : one wave per c-row */
    int lane = tid & 63;
    int t0 = tq * 32;

    float4 vreg[8];
    auto load_regs = [&](int g) {
        int c = cg * 32 + g * 8 + wv;
        const float* src = x + ((size_t)(b * C_ + c) * 128 + t0) * 64 + lane * 4;
        #pragma unroll
        for (int i = 0; i < 8; i++)
            vreg[i] = *(const float4*)(src + i * 256);
    };

    load_regs(0);
    for (int g = 0; g < 4; g++) {
        /* commit wave's c-row to LDS + per-(c,v) partial sum over 32 t */
        float4 s4 = {0.f, 0.f, 0.f, 0.f};
        #pragma unroll
        for (int i = 0; i < 8; i++) {
            *(float4*)&L[wv * 2048 + i * 256 + lane * 4] = vreg[i];
            s4.x += vreg[i].x; s4.y += vreg[i].y;
            s4.z += vreg[i].z; s4.w += vreg[i].w;
        }
        /* lanes {l, l^16, l^32, l^48} hold same v range -> reduce over t-groups */
        s4.x += __shfl_xor(s4.x, 16, 64); s4.y += __shfl_xor(s4.y, 16, 64);
        s4.z += __shfl_xor(s4.z, 16, 64); s4.w += __shfl_xor(s4.w, 16, 64);
        s4.x += __shfl_xor(s4.x, 32, 64); s4.y += __shfl_xor(s4.y, 32, 64);
        s4.z += __shfl_xor(s4.z, 32, 64); s4.w += __shfl_xor(s4.w, 32, 64);
        if (lane < 16) {
            int c = cg * 32 + g * 8 + wv;
            const float r = 1.0f / (float)T_;
            float* dst = tp + (size_t)(b * C_ + c) * V_ + lane * 4;
            atomicAdd(&dst[0], s4.x * r); atomicAdd(&dst[1], s4.y * r);
            atomicAdd(&dst[2], s4.z * r); atomicAdd(&dst[3], s4.w * r);
        }
        __syncthreads();
        if (g < 3) load_regs(g + 1);    /* next pass in flight under pack */

        /* pack: output group (cc=cg, q=g); 4 sub-steps x 8 t-rows, 512 threads */
        int v = tid & 63, tw = tid >> 6;   /* tw 0..7 */
        size_t obase = ((size_t)(b * 128 + t0) * 8 + cg) * 2048 + g * 512 + (size_t)v * 8;
        #pragma unroll
        for (int s = 0; s < 4; s++) {
            int tl = s * 8 + tw;
            const float* Lp = &L[tl * 64 + v];
            uint4 u;
            u.x = pack2(Lp[0 * 2048], Lp[1 * 2048]);
            u.y = pack2(Lp[2 * 2048], Lp[3 * 2048]);
            u.z = pack2(Lp[4 * 2048], Lp[5 * 2048]);
            u.w = pack2(Lp[6 * 2048], Lp[7 * 2048]);
            *(uint4*)(img + obase + (size_t)tl * 16384) = u;
        }
        __syncthreads();
    }
}

/* x1/x2 partials over 64-c chunk, atomic into zeroed x1/x2 */
__global__ __launch_bounds__(256) void k_x1x2a(const float* __restrict__ tp,
                                               const float* __restrict__ w1, const float* __restrict__ b1,
                                               const float* __restrict__ w2, const float* __restrict__ b2,
                                               float* __restrict__ x1, float* __restrict__ x2) {
    int og = blockIdx.x, cc = blockIdx.y, b = blockIdx.z;
    int o  = og * 16 + (threadIdx.x >> 4);
    int v4 = threadIdx.x & 15;
    const float4* ptp = (const float4*)(tp + (size_t)b * C_ * V_) + v4;
    float4 s1 = {0.f,0.f,0.f,0.f}, s2 = {0.f,0.f,0.f,0.f};
    int c0 = cc * 64;
    for (int c = c0; c < c0 + 64; c++) {
        float4 tv = ptp[c * 16];
        float wa = w1[o * C_ + c];
        float wb = w2[o * C_ + c];
        s1.x += tv.x * wa; s1.y += tv.y * wa; s1.z += tv.z * wa; s1.w += tv.w * wa;
        s2.x += tv.x * wb; s2.y += tv.y * wb; s2.z += tv.z * wb; s2.w += tv.w * wb;
    }
    if (cc == 0) {
        float bv1 = b1[o], bv2 = b2[o];
        s1.x += bv1; s1.y += bv1; s1.z += bv1; s1.w += bv1;
        s2.x += bv2; s2.y += bv2; s2.z += bv2; s2.w += bv2;
    }
    float* p1 = x1 + (size_t)(b * O_ + o) * V_ + v4 * 4;
    float* p2 = x2 + (size_t)(b * O_ + o) * V_ + v4 * 4;
    atomicAdd(&p1[0], s1.x); atomicAdd(&p1[1], s1.y); atomicAdd(&p1[2], s1.z); atomicAdd(&p1[3], s1.w);
    atomicAdd(&p2[0], s2.x); atomicAdd(&p2[1], s2.y); atomicAdd(&p2[2], s2.z); atomicAdd(&p2[3], s2.w);
}

/* ada[b,k,v,w] = softmax_v( sum_c x1[b,k,c,v]*x2[b,k,c,w] ) one wave per (b,k,w) */
__global__ __launch_bounds__(64) void k_ada(const float* __restrict__ x1,
                                            const float* __restrict__ x2,
                                            float* __restrict__ ada) {
    int bid = blockIdx.x;
    int w = bid & 63;
    int k = (bid >> 6) & 7;
    int b = bid >> 9;
    int v = threadIdx.x;
    const float* p1 = x1 + ((size_t)b * O_ + k * 32) * V_;
    const float* p2 = x2 + ((size_t)b * O_ + k * 32) * V_;
    float s = 0.f;
    #pragma unroll
    for (int c = 0; c < 32; c++) s += p1[c * V_ + v] * p2[c * V_ + w];
    float m = s;
    #pragma unroll
    for (int off = 32; off >= 1; off >>= 1) m = fmaxf(m, __shfl_xor(m, off, 64));
    float e = __expf(s - m);
    float sum = e;
    #pragma unroll
    for (int off = 32; off >= 1; off >>= 1) sum += __shfl_xor(sum, off, 64);
    ada[((size_t)(b * K_ + k) * V_ + v) * V_ + w] = e / sum;
}

/* NEW: build the combined A matrix ONCE as a bf16 MFMA fragment image.
   Aimg[b][k][c][w][v] = A_param[k][v][w] + beta*ada[b][k][v][w]
                         + alpha*tanh(x1[b,k*32+c,v] - x2[b,k*32+c,w])
   Previously this (incl. 2x-duplicated tanh over mh) was the k_einsum prologue:
   128 tanh/lane on its serial critical path + conflicted Coms LDS reads. */
__global__ __launch_bounds__(256) void k_actr(const float* __restrict__ x1,
                                              const float* __restrict__ x2,
                                              const float* __restrict__ ada,
                                              const float* __restrict__ A_param,
                                              const float* __restrict__ alphap,
                                              const float* __restrict__ betap,
                                              ushort_t* __restrict__ Aimg) {
    __shared__ float ComT[64][65];   /* [w][v], padded: bank = (w+v)%32 */
    __shared__ float x1s[4][64];
    __shared__ float x2s[4][64];
    int cq = blockIdx.x;   /* 0..7 : c-range cq*4 .. +3 */
    int k  = blockIdx.y;
    int b  = blockIdx.z;
    int tid = threadIdx.x;
    float alpha = alphap[0], beta = betap[0];
    const float* Apk = A_param + (size_t)k * 4096;
    const float* adk = ada + (size_t)(b * K_ + k) * 4096;
    #pragma unroll
    for (int i = 0; i < 4; i++) {
        int e4 = tid + i * 256;          /* float4 index over [v][w] */
        int v = e4 >> 4, w4 = (e4 & 15) * 4;
        float4 ap = *(const float4*)(Apk + (size_t)e4 * 4);
        float4 ad = *(const float4*)(adk + (size_t)e4 * 4);
        ComT[w4 + 0][v] = ap.x + beta * ad.x;
        ComT[w4 + 1][v] = ap.y + beta * ad.y;
        ComT[w4 + 2][v] = ap.z + beta * ad.z;
        ComT[w4 + 3][v] = ap.w + beta * ad.w;
    }
    {
        int cl = tid >> 6, v = tid & 63;
        int o1 = k * 32 + cq * 4 + cl;
        x1s[cl][v] = x1[((size_t)b * O_ + o1) * V_ + v];
        x2s[cl][v] = x2[((size_t)b * O_ + o1) * V_ + v];
    }
    __syncthreads();
    /* items: idx = it*256+tid -> vb = idx&7, w = (idx>>3)&63, c = idx>>9 */
    #pragma unroll
    for (int it = 0; it < 8; it++) {
        int idx = it * 256 + tid;
        int vb = idx & 7, w = (idx >> 3) & 63, c = idx >> 9;
        float x2v = x2s[c][w];
        float av[8];
        #pragma unroll
        for (int j = 0; j < 8; j++) {
            int v = vb * 8 + j;
            float d = x1s[c][v] - x2v;
            float ax = fabsf(d);
            float e2 = __expf(-2.f * ax);
            float th = copysignf((1.f - e2) / (1.f + e2), d);
            av[j] = ComT[w][v] + alpha * th;
        }
        uint4 bp;
        bp.x = pack2(av[0], av[1]); bp.y = pack2(av[2], av[3]);
        bp.z = pack2(av[4], av[5]); bp.w = pack2(av[6], av[7]);
        *(uint4*)(Aimg + (size_t)((b * K_ + k) * 32 + cq * 4 + c) * 4096 + w * 64 + vb * 8) = bp;
    }
}

/* w[256][256] fp32 -> bf16 image: [cc 8][q 4][ol 256][cl 8] */
__global__ __launch_bounds__(256) void k_wconv(const float* __restrict__ w,
                                               ushort_t* __restrict__ img) {
    int flat = blockIdx.x * 256 + threadIdx.x;
    #pragma unroll
    for (int g2 = 0; g2 < 2; g2++) {
        int gi = flat * 2 + g2;
        int cc = gi >> 10;
        int q  = (gi >> 8) & 3;
        int ol = gi & 255;
        int c0 = cc * 32 + q * 8;
        const float* src = w + (size_t)ol * C_ + c0;
        float4 f0 = *(const float4*)src;
        float4 f1 = *(const float4*)(src + 4);
        uint4 u;
        u.x = pack2(f0.x, f0.y); u.y = pack2(f0.z, f0.w);
        u.z = pack2(f1.x, f1.y); u.w = pack2(f1.z, f1.w);
        *(uint4*)(img + (size_t)gi * 8) = u;
    }
}

/* out[b][o][n] = bf16( sum_c W[o][c] X[b][n][c] + bias[o] ); fused exact-fp32 BN stats
   into sliced accumulators psum/psumsq [NSL][256]. */
__global__ __launch_bounds__(256) void k_gemm(const ushort_t* __restrict__ ximg,
                                              const ushort_t* __restrict__ wimg,
                                              const float* __restrict__ bias,
                                              ushort_t* __restrict__ out,
                                              float* __restrict__ psum,
                                              float* __restrict__ psumsq) {
    __shared__ __align__(16) ushort_t sh[2048];
    int tid = threadIdx.x;
    int nblk = blockIdx.x, b = blockIdx.z;
    int wm = tid >> 6;
    int lane = tid & 63, ln = lane & 15, q = lane >> 4;
    f32x4 acc[4][4];
    #pragma unroll
    for (int mt = 0; mt < 4; mt++)
        #pragma unroll
        for (int nt = 0; nt < 4; nt++) acc[mt][nt] = (f32x4){0.f, 0.f, 0.f, 0.f};
    const ushort_t* xbase = ximg + ((size_t)(b * 128 + nblk) * 8) * 2048;
    for (int cc = 0; cc < 8; cc++) {
        gload_lds16(xbase + (size_t)cc * 2048 + wm * 512 + lane * 8, &sh[wm * 512]);
        __syncthreads();
        short8 a[4], bb[4];
        const ushort_t* wc = wimg + (size_t)cc * 8192 + q * 2048;
        #pragma unroll
        for (int mt = 0; mt < 4; mt++)
            a[mt] = *(const short8*)(wc + (wm * 64 + mt * 16 + ln) * 8);
        #pragma unroll
        for (int nt = 0; nt < 4; nt++)
            bb[nt] = *(const short8*)&sh[q * 512 + (nt * 16 + ln) * 8];
        #pragma unroll
        for (int mt = 0; mt < 4; mt++)
            #pragma unroll
            for (int nt = 0; nt < 4; nt++)
                acc[mt][nt] = __builtin_amdgcn_mfma_f32_16x16x32_bf16(a[mt], bb[nt], acc[mt][nt], 0, 0, 0);
        __syncthreads();
    }
    int n_base = nblk * 64;
    int slice = (nblk ^ (b << 3)) & (NSL - 1);
    #pragma unroll
    for (int mt = 0; mt < 4; mt++) {
        int o0 = wm * 64 + mt * 16 + q * 4;
        #pragma unroll
        for (int r = 0; r < 4; r++) {
            float bv = bias[o0 + r];
            float v0 = acc[mt][0][r] + bv, v1 = acc[mt][1][r] + bv;
            float v2 = acc[mt][2][r] + bv, v3 = acc[mt][3][r] + bv;
            ushort_t* orow = out + ((size_t)(b * O_ + o0 + r)) * TN + n_base + ln;
            orow[0] = f2bf(v0); orow[16] = f2bf(v1); orow[32] = f2bf(v2); orow[48] = f2bf(v3);
            float s  = v0 + v1 + v2 + v3;
            float sq = v0 * v0 + v1 * v1 + v2 * v2 + v3 * v3;
            #pragma unroll
            for (int off = 1; off <= 8; off <<= 1) {
                s  += __shfl_xor(s,  off, 64);
                sq += __shfl_xor(sq, off, 64);
            }
            if (ln == 0) {
                atomicAdd(&psum[slice * 256 + o0 + r],   s);
                atomicAdd(&psumsq[slice * 256 + o0 + r], sq);
            }
        }
    }
}

__global__ void k_finalize(const float* __restrict__ psum, const float* __restrict__ psumsq,
                           const float* __restrict__ gamma, const float* __restrict__ betap,
                           float* __restrict__ scale, float* __restrict__ shift) {
    int o = threadIdx.x;
    float s = 0.f, sq = 0.f;
    #pragma unroll
    for (int sl = 0; sl < NSL; sl++) {
        s  += psum[sl * 256 + o];
        sq += psumsq[sl * 256 + o];
    }
    float mean = s  * (1.0f / (float)NBT);
    float var  = sq * (1.0f / (float)NBT) - mean * mean;
    float sc = gamma[o] * rsqrtf(var + 1e-5f);
    scale[o] = sc;
    shift[o] = betap[o] - mean * sc;
}

/* MFMA einsum: per block (b,k,q,mh): 8 channels o1=k*32+q*8+cl, t-range mh*64..+63.
   h2img[(b*128+t)*8+k, q*512 + w*8 + cl] = sum_v relu(bn(z[b,o1,t,v])) * A[b,k,c,v,w]
   v2: A comes precomputed (k_actr) as bf16 fragments -> prologue is 16 coalesced
   16B loads instead of 128 tanh + conflicted LDS. stg rows padded 512->520 ushorts
   (qq-rows shift 16 banks: 8-way write conflict -> 4-way). */
__global__ __launch_bounds__(256) void k_einsum_mfma(const ushort_t* __restrict__ z,
                                                     const ushort_t* __restrict__ Aimg,
                                                     const float* __restrict__ scale,
                                                     const float* __restrict__ shift,
                                                     ushort_t* __restrict__ h2img) {
    __shared__ __align__(16) ushort_t stg[16 * 520];
    int tid = threadIdx.x;
    int bid = blockIdx.x;
    int mh = bid & 1;
    int q  = (bid >> 1) & 3;
    int k  = (bid >> 3) & 7;
    int b  = bid >> 6;
    int wm = tid >> 6;
    int lane = tid & 63, ln = lane & 15, qq = lane >> 4;

    short8 bfrag[2][2][4];
    const ushort_t* Ab = Aimg + (size_t)((b * K_ + k) * 32 + q * 8) * 4096;
    #pragma unroll
    for (int half = 0; half < 2; half++) {
        int cl = wm + half * 4;
        #pragma unroll
        for (int kk = 0; kk < 2; kk++)
            #pragma unroll
            for (int nt = 0; nt < 4; nt++)
                bfrag[half][kk][nt] = *(const short8*)(Ab + (size_t)cl * 4096
                                                      + (nt * 16 + ln) * 64 + kk * 32 + qq * 8);
    }

    int o1a = k * 32 + q * 8 + wm;
    int o1b = o1a + 4;
    float scv[2] = {scale[o1a], scale[o1b]};
    float shv[2] = {shift[o1a], shift[o1b]};
    const ushort_t* zr[2] = {z + ((size_t)b * O_ + o1a) * TN, z + ((size_t)b * O_ + o1b) * TN};
    size_t obase = ((size_t)(b * 128) * 8 + k) * 2048 + q * 512;

    for (int mt = mh * 4; mt < mh * 4 + 4; mt++) {
        f32x4 acc[2][4];
        #pragma unroll
        for (int half = 0; half < 2; half++)
            #pragma unroll
            for (int nt = 0; nt < 4; nt++) acc[half][nt] = (f32x4){0.f, 0.f, 0.f, 0.f};
        #pragma unroll
        for (int half = 0; half < 2; half++) {
            float s = scv[half], h = shv[half];
            #pragma unroll
            for (int kk = 0; kk < 2; kk++) {
                const ushort_t* src = zr[half] + (mt * 16 + ln) * 64 + kk * 32 + qq * 8;
                uint4 zv = *(const uint4*)src;
                float f0 = bf2f_lo(zv.x), f1 = bf2f_hi(zv.x);
                float f2 = bf2f_lo(zv.y), f3 = bf2f_hi(zv.y);
                float f4 = bf2f_lo(zv.z), f5 = bf2f_hi(zv.z);
                float f6 = bf2f_lo(zv.w), f7 = bf2f_hi(zv.w);
                uint4 hp;
                hp.x = pack2(fmaxf(f0 * s + h, 0.f), fmaxf(f1 * s + h, 0.f));
                hp.y = pack2(fmaxf(f2 * s + h, 0.f), fmaxf(f3 * s + h, 0.f));
                hp.z = pack2(fmaxf(f4 * s + h, 0.f), fmaxf(f5 * s + h, 0.f));
                hp.w = pack2(fmaxf(f6 * s + h, 0.f), fmaxf(f7 * s + h, 0.f));
                short8 hf = __builtin_bit_cast(short8, hp);
                #pragma unroll
                for (int nt = 0; nt < 4; nt++)
                    acc[half][nt] = __builtin_amdgcn_mfma_f32_16x16x32_bf16(hf, bfrag[half][kk][nt], acc[half][nt], 0, 0, 0);
            }
        }
        #pragma unroll
        for (int half = 0; half < 2; half++) {
            int cl = wm + half * 4;
            #pragma unroll
            for (int nt = 0; nt < 4; nt++)
                #pragma unroll
                for (int r = 0; r < 4; r++)
                    stg[(qq * 4 + r) * 520 + (nt * 16 + ln) * 8 + cl] = f2bf(acc[half][nt][r]);
        }
        __syncthreads();
        #pragma unroll
        for (int ii = 0; ii < 4; ii++) {
            int u = tid + ii * 256;
            int tl = u >> 6, off = u & 63;
            ((uint4*)(h2img + obase + (size_t)(mt * 16 + tl) * 16384))[off] =
                ((const uint4*)stg)[tl * 65 + off];
        }
        __syncthreads();
    }
}

/* out = relu(bn(u) + x); u is bf16 pre-BN, out fp32 */
__global__ __launch_bounds__(256) void k_final(const ushort_t* __restrict__ ub,
                                               const float* __restrict__ x,
                                               const float* __restrict__ scale,
                                               const float* __restrict__ shift,
                                               float* __restrict__ out) {
    size_t i4 = (size_t)blockIdx.x * 256 + threadIdx.x;
    int o = (int)((i4 >> 11) & 255);
    uint2 uv = ((const uint2*)ub)[i4];
    float4 xv = ((const float4*)x)[i4];
    float sc = scale[o], sh = shift[o];
    float4 r;
    r.x = fmaxf(bf2f_lo(uv.x) * sc + sh + xv.x, 0.f);
    r.y = fmaxf(bf2f_hi(uv.x) * sc + sh + xv.y, 0.f);
    r.z = fmaxf(bf2f_lo(uv.y) * sc + sh + xv.z, 0.f);
    r.w = fmaxf(bf2f_hi(uv.y) * sc + sh + xv.w, 0.f);
    ((float4*)out)[i4] = r;
}

extern "C" void kernel_launch(void* const* d_in, const int* in_sizes, int n_in,
                              void* d_out, int out_size, void* d_ws, size_t ws_size,
                              hipStream_t stream) {
    const float* x          = (const float*)d_in[0];
    const float* A_param    = (const float*)d_in[1];
    const float* alphap     = (const float*)d_in[2];
    const float* betap      = (const float*)d_in[3];
    const float* w1         = (const float*)d_in[4];
    const float* b1         = (const float*)d_in[5];
    const float* w2         = (const float*)d_in[6];
    const float* b2         = (const float*)d_in[7];
    const float* stem_w     = (const float*)d_in[8];
    const float* stem_b     = (const float*)d_in[9];
    const float* stem_gamma = (const float*)d_in[10];
    const float* stem_beta  = (const float*)d_in[11];
    const float* head_w     = (const float*)d_in[12];
    const float* head_b     = (const float*)d_in[13];
    const float* head_gamma = (const float*)d_in[14];
    const float* head_beta  = (const float*)d_in[15];

    float* W      = (float*)d_ws;
    float* tp     = W + OFF_TP;
    float* x1b    = W + OFF_X1;
    float* x2b    = W + OFF_X2;
    float* ssum   = W + OFF_STATS;               /* [NSL][256] */
    float* ssq    = W + OFF_STATS + NSL * 256;
    float* hsum   = W + OFF_STATS + NSL * 512;
    float* hsq    = W + OFF_STATS + NSL * 768;
    float* sscale = W + OFF_SSC;
    float* sshift = W + OFF_SSC + 256;
    float* hscale = W + OFF_HSC;
    float* hshift = W + OFF_HSC + 256;
    float* adab   = W + OFF_ADA;
    float* uout   = (float*)d_out;

    ushort_t* xTimg  = (ushort_t*)d_out;          /* d_out[0 .. 67MB): dead before k_final */
    ushort_t* Aimgu  = (ushort_t*)((float*)d_out + 16777216);  /* d_out upper half: A image 33.5MB */
    ushort_t* wsimg  = (ushort_t*)(W + OFF_TP);   /* tp region, after x1x2 */
    ushort_t* whimg  = (ushort_t*)(W + OFF_TP + 32768);
    ushort_t* zb16   = (ushort_t*)(W + OFF_Z);    /* z bf16; u reuses it after einsum */
    ushort_t* ub16   = zb16;
    ushort_t* h2img  = (ushort_t*)(W + OFF_H2);

    /* zero tp, x1, x2, sliced stats (contiguous) */
    hipMemsetAsync(W, 0, (size_t)(OFF_STATS + NSL * 1024) * sizeof(float), stream);

    k_xpose2<<<dim3(4, 8, 16), 512, 0, stream>>>(x, xTimg, tp);
    k_x1x2a<<<dim3(16, 4, 16), 256, 0, stream>>>(tp, w1, b1, w2, b2, x1b, x2b);
    k_ada<<<8192, 64, 0, stream>>>(x1b, x2b, adab);
    k_actr<<<dim3(8, 8, 16), 256, 0, stream>>>(x1b, x2b, adab, A_param, alphap, betap, Aimgu);
    k_wconv<<<16, 256, 0, stream>>>(stem_w, wsimg);
    k_wconv<<<16, 256, 0, stream>>>(head_w, whimg);

    k_gemm<<<dim3(128, 1, 16), 256, 0, stream>>>(xTimg, wsimg, stem_b, zb16, ssum, ssq);
    k_finalize<<<1, 256, 0, stream>>>(ssum, ssq, stem_gamma, stem_beta, sscale, sshift);

    k_einsum_mfma<<<1024, 256, 0, stream>>>(zb16, Aimgu, sscale, sshift, h2img);

    k_gemm<<<dim3(128, 1, 16), 256, 0, stream>>>(h2img, whimg, head_b, ub16, hsum, hsq);
    k_finalize<<<1, 256, 0, stream>>>(hsum, hsq, head_gamma, head_beta, hscale, hshift);
    k_final<<<32768, 256, 0, stream>>>(ub16, x, hscale, hshift, uout);
}

// Round 5
// 485.623 us; speedup vs baseline: 1.0591x; 1.0591x over previous
//
#include <hip/hip_runtime.h>
#include <cstdint>
#include <cstddef>

#define B_ 16
#define C_ 256
#define T_ 128
#define V_ 64
#define K_ 8
#define O_ 256
#define TN 8192      /* T_*V_ */
#define NBT 131072   /* B_*T_*V_ : BN sample count */
#define NSL 32       /* stats slices (atomic contention spreader) */

typedef unsigned short ushort_t;
typedef __attribute__((ext_vector_type(8))) short short8;
typedef __attribute__((ext_vector_type(4))) float f32x4;

/* ---- workspace layout (float offsets) ---- */
#define OFF_TP     0          /* [B][C][V] 262144; reused for w-images (bf16) after x1x2 */
#define OFF_X1     262144
#define OFF_X2     524288
#define OFF_STATS  786432     /* 4 arrays x [NSL][256] = 32768 */
#define OFF_SSC    819200     /* stem scale/shift 512 (unused now) */
#define OFF_HSC    819712
#define OFF_ADA    820224     /* [B][K][V][V] 524288 -> ends 1344512 */
#define OFF_Z      1344512    /* z bf16 [B][O][TN] : 33554432 ushort = 16777216 f32; u reuses it */
#define OFF_H2     34867200   /* h2 bf16 image 33554432 ushort */

__device__ inline ushort_t f2bf(float f) {
    unsigned u = __builtin_bit_cast(unsigned, f);
    unsigned r = (u + 0x7FFFu + ((u >> 16) & 1u)) >> 16;
    return (ushort_t)r;
}
__device__ inline unsigned pack2(float a, float b) {
    return (unsigned)f2bf(a) | ((unsigned)f2bf(b) << 16);
}
__device__ inline float bf2f_lo(unsigned u) { return __builtin_bit_cast(float, u << 16); }
__device__ inline float bf2f_hi(unsigned u) { return __builtin_bit_cast(float, u & 0xFFFF0000u); }
__device__ inline void gload_lds16(const void* g, void* l) {
    __builtin_amdgcn_global_load_lds((const __attribute__((address_space(1))) unsigned int*)g,
                                     (__attribute__((address_space(3))) unsigned int*)l, 16, 0, 0);
}

/* x [b][c][t][v] fp32 -> bf16 frag image ((b*128+t)*8+cc)*2048 + q*512 + v*8 + cl
   (c = cc*32+q*8+cl); fused per-(b,c,v) mean over t.
   v4: each WAVE reads one c-row contiguously (8KB = 32t x 64v) -- fixes the HBM
   channel hotspot of v1/v2 (same-t bursts, 1.2 TB/s read ceiling). 512 threads. */
__global__ __launch_bounds__(512) void k_xpose2(const float* __restrict__ x,
                                                ushort_t* __restrict__ img,
                                                float* __restrict__ tp) {
    __shared__ float L[8 * 2048];   /* [c 8][t 32][v 64] */
    int tq = blockIdx.x;            /* 0..3 : t-range tq*32 .. +31 */
    int cg = blockIdx.y;            /* 0..7 : c-range cg*32 .. +31 */
    int b  = blockIdx.z;
    int tid  = threadIdx.x;
    int wv   = tid >> 6;            /* 0..7 : one wave per c-row */
    int lane = tid & 63;
    int t0 = tq * 32;

    float4 vreg[8];
    auto load_regs = [&](int g) {
        int c = cg * 32 + g * 8 + wv;
        const float* src = x + ((size_t)(b * C_ + c) * 128 + t0) * 64 + lane * 4;
        #pragma unroll
        for (int i = 0; i < 8; i++)
            vreg[i] = *(const float4*)(src + i * 256);
    };

    load_regs(0);
    for (int g = 0; g < 4; g++) {
        /* commit wave's c-row to LDS + per-(c,v) partial sum over 32 t */
        float4 s4 = {0.f, 0.f, 0.f, 0.f};
        #pragma unroll
        for (int i = 0; i < 8; i++) {
            *(float4*)&L[wv * 2048 + i * 256 + lane * 4] = vreg[i];
            s4.x += vreg[i].x; s4.y += vreg[i].y;
            s4.z += vreg[i].z; s4.w += vreg[i].w;
        }
        /* lanes {l, l^16, l^32, l^48} hold same v range -> reduce over t-groups */
        s4.x += __shfl_xor(s4.x, 16, 64); s4.y += __shfl_xor(s4.y, 16, 64);
        s4.z += __shfl_xor(s4.z, 16, 64); s4.w += __shfl_xor(s4.w, 16, 64);
        s4.x += __shfl_xor(s4.x, 32, 64); s4.y += __shfl_xor(s4.y, 32, 64);
        s4.z += __shfl_xor(s4.z, 32, 64); s4.w += __shfl_xor(s4.w, 32, 64);
        if (lane < 16) {
            int c = cg * 32 + g * 8 + wv;
            const float r = 1.0f / (float)T_;
            float* dst = tp + (size_t)(b * C_ + c) * V_ + lane * 4;
            atomicAdd(&dst[0], s4.x * r); atomicAdd(&dst[1], s4.y * r);
            atomicAdd(&dst[2], s4.z * r); atomicAdd(&dst[3], s4.w * r);
        }
        __syncthreads();
        if (g < 3) load_regs(g + 1);    /* next pass in flight under pack */

        /* pack: output group (cc=cg, q=g); 4 sub-steps x 8 t-rows, 512 threads */
        int v = tid & 63, tw = tid >> 6;   /* tw 0..7 */
        size_t obase = ((size_t)(b * 128 + t0) * 8 + cg) * 2048 + g * 512 + (size_t)v * 8;
        #pragma unroll
        for (int s = 0; s < 4; s++) {
            int tl = s * 8 + tw;
            const float* Lp = &L[tl * 64 + v];
            uint4 u;
            u.x = pack2(Lp[0 * 2048], Lp[1 * 2048]);
            u.y = pack2(Lp[2 * 2048], Lp[3 * 2048]);
            u.z = pack2(Lp[4 * 2048], Lp[5 * 2048]);
            u.w = pack2(Lp[6 * 2048], Lp[7 * 2048]);
            *(uint4*)(img + obase + (size_t)tl * 16384) = u;
        }
        __syncthreads();
    }
}

/* x1/x2 partials over 64-c chunk, atomic into zeroed x1/x2 */
__global__ __launch_bounds__(256) void k_x1x2a(const float* __restrict__ tp,
                                               const float* __restrict__ w1, const float* __restrict__ b1,
                                               const float* __restrict__ w2, const float* __restrict__ b2,
                                               float* __restrict__ x1, float* __restrict__ x2) {
    int og = blockIdx.x, cc = blockIdx.y, b = blockIdx.z;
    int o  = og * 16 + (threadIdx.x >> 4);
    int v4 = threadIdx.x & 15;
    const float4* ptp = (const float4*)(tp + (size_t)b * C_ * V_) + v4;
    float4 s1 = {0.f,0.f,0.f,0.f}, s2 = {0.f,0.f,0.f,0.f};
    int c0 = cc * 64;
    for (int c = c0; c < c0 + 64; c++) {
        float4 tv = ptp[c * 16];
        float wa = w1[o * C_ + c];
        float wb = w2[o * C_ + c];
        s1.x += tv.x * wa; s1.y += tv.y * wa; s1.z += tv.z * wa; s1.w += tv.w * wa;
        s2.x += tv.x * wb; s2.y += tv.y * wb; s2.z += tv.z * wb; s2.w += tv.w * wb;
    }
    if (cc == 0) {
        float bv1 = b1[o], bv2 = b2[o];
        s1.x += bv1; s1.y += bv1; s1.z += bv1; s1.w += bv1;
        s2.x += bv2; s2.y += bv2; s2.z += bv2; s2.w += bv2;
    }
    float* p1 = x1 + (size_t)(b * O_ + o) * V_ + v4 * 4;
    float* p2 = x2 + (size_t)(b * O_ + o) * V_ + v4 * 4;
    atomicAdd(&p1[0], s1.x); atomicAdd(&p1[1], s1.y); atomicAdd(&p1[2], s1.z); atomicAdd(&p1[3], s1.w);
    atomicAdd(&p2[0], s2.x); atomicAdd(&p2[1], s2.y); atomicAdd(&p2[2], s2.z); atomicAdd(&p2[3], s2.w);
}

/* ada[b,k,v,w] = softmax_v( sum_c x1[b,k,c,v]*x2[b,k,c,w] ) one wave per (b,k,w) */
__global__ __launch_bounds__(64) void k_ada(const float* __restrict__ x1,
                                            const float* __restrict__ x2,
                                            float* __restrict__ ada) {
    int bid = blockIdx.x;
    int w = bid & 63;
    int k = (bid >> 6) & 7;
    int b = bid >> 9;
    int v = threadIdx.x;
    const float* p1 = x1 + ((size_t)b * O_ + k * 32) * V_;
    const float* p2 = x2 + ((size_t)b * O_ + k * 32) * V_;
    float s = 0.f;
    #pragma unroll
    for (int c = 0; c < 32; c++) s += p1[c * V_ + v] * p2[c * V_ + w];
    float m = s;
    #pragma unroll
    for (int off = 32; off >= 1; off >>= 1) m = fmaxf(m, __shfl_xor(m, off, 64));
    float e = __expf(s - m);
    float sum = e;
    #pragma unroll
    for (int off = 32; off >= 1; off >>= 1) sum += __shfl_xor(sum, off, 64);
    ada[((size_t)(b * K_ + k) * V_ + v) * V_ + w] = e / sum;
}

/* w[256][256] fp32 -> bf16 image: [cc 8][q 4][ol 256][cl 8]; blockIdx.y picks stem/head */
__global__ __launch_bounds__(256) void k_wconv(const float* __restrict__ ws,
                                               const float* __restrict__ wh,
                                               ushort_t* __restrict__ img) {
    const float* w = blockIdx.y ? wh : ws;
    ushort_t* dst = img + (size_t)blockIdx.y * 65536;
    int flat = blockIdx.x * 256 + threadIdx.x;
    #pragma unroll
    for (int g2 = 0; g2 < 2; g2++) {
        int gi = flat * 2 + g2;
        int cc = gi >> 10;
        int q  = (gi >> 8) & 3;
        int ol = gi & 255;
        int c0 = cc * 32 + q * 8;
        const float* src = w + (size_t)ol * C_ + c0;
        float4 f0 = *(const float4*)src;
        float4 f1 = *(const float4*)(src + 4);
        uint4 u;
        u.x = pack2(f0.x, f0.y); u.y = pack2(f0.z, f0.w);
        u.z = pack2(f1.x, f1.y); u.w = pack2(f1.z, f1.w);
        *(uint4*)(dst + (size_t)gi * 8) = u;
    }
}

/* out[b][o][n] = bf16( sum_c W[o][c] X[b][n][c] + bias[o] ); fused exact-fp32 BN stats
   into sliced accumulators psum/psumsq [NSL][256]. */
__global__ __launch_bounds__(256) void k_gemm(const ushort_t* __restrict__ ximg,
                                              const ushort_t* __restrict__ wimg,
                                              const float* __restrict__ bias,
                                              ushort_t* __restrict__ out,
                                              float* __restrict__ psum,
                                              float* __restrict__ psumsq) {
    __shared__ __align__(16) ushort_t sh[2048];
    int tid = threadIdx.x;
    int nblk = blockIdx.x, b = blockIdx.z;
    int wm = tid >> 6;
    int lane = tid & 63, ln = lane & 15, q = lane >> 4;
    f32x4 acc[4][4];
    #pragma unroll
    for (int mt = 0; mt < 4; mt++)
        #pragma unroll
        for (int nt = 0; nt < 4; nt++) acc[mt][nt] = (f32x4){0.f, 0.f, 0.f, 0.f};
    const ushort_t* xbase = ximg + ((size_t)(b * 128 + nblk) * 8) * 2048;
    for (int cc = 0; cc < 8; cc++) {
        gload_lds16(xbase + (size_t)cc * 2048 + wm * 512 + lane * 8, &sh[wm * 512]);
        __syncthreads();
        short8 a[4], bb[4];
        const ushort_t* wc = wimg + (size_t)cc * 8192 + q * 2048;
        #pragma unroll
        for (int mt = 0; mt < 4; mt++)
            a[mt] = *(const short8*)(wc + (wm * 64 + mt * 16 + ln) * 8);
        #pragma unroll
        for (int nt = 0; nt < 4; nt++)
            bb[nt] = *(const short8*)&sh[q * 512 + (nt * 16 + ln) * 8];
        #pragma unroll
        for (int mt = 0; mt < 4; mt++)
            #pragma unroll
            for (int nt = 0; nt < 4; nt++)
                acc[mt][nt] = __builtin_amdgcn_mfma_f32_16x16x32_bf16(a[mt], bb[nt], acc[mt][nt], 0, 0, 0);
        __syncthreads();
    }
    int n_base = nblk * 64;
    int slice = (nblk ^ (b << 3)) & (NSL - 1);
    #pragma unroll
    for (int mt = 0; mt < 4; mt++) {
        int o0 = wm * 64 + mt * 16 + q * 4;
        #pragma unroll
        for (int r = 0; r < 4; r++) {
            float bv = bias[o0 + r];
            float v0 = acc[mt][0][r] + bv, v1 = acc[mt][1][r] + bv;
            float v2 = acc[mt][2][r] + bv, v3 = acc[mt][3][r] + bv;
            ushort_t* orow = out + ((size_t)(b * O_ + o0 + r)) * TN + n_base + ln;
            orow[0] = f2bf(v0); orow[16] = f2bf(v1); orow[32] = f2bf(v2); orow[48] = f2bf(v3);
            float s  = v0 + v1 + v2 + v3;
            float sq = v0 * v0 + v1 * v1 + v2 * v2 + v3 * v3;
            #pragma unroll
            for (int off = 1; off <= 8; off <<= 1) {
                s  += __shfl_xor(s,  off, 64);
                sq += __shfl_xor(sq, off, 64);
            }
            if (ln == 0) {
                atomicAdd(&psum[slice * 256 + o0 + r],   s);
                atomicAdd(&psumsq[slice * 256 + o0 + r], sq);
            }
        }
    }
}

__global__ void k_finalize(const float* __restrict__ psum, const float* __restrict__ psumsq,
                           const float* __restrict__ gamma, const float* __restrict__ betap,
                           float* __restrict__ scale, float* __restrict__ shift) {
    int o = threadIdx.x;
    float s = 0.f, sq = 0.f;
    #pragma unroll
    for (int sl = 0; sl < NSL; sl++) {
        s  += psum[sl * 256 + o];
        sq += psumsq[sl * 256 + o];
    }
    float mean = s  * (1.0f / (float)NBT);
    float var  = sq * (1.0f / (float)NBT) - mean * mean;
    float sc = gamma[o] * rsqrtf(var + 1e-5f);
    scale[o] = sc;
    shift[o] = betap[o] - mean * sc;
}

/* MFMA einsum: per block (b,k,q): 8 channels o1=k*32+q*8+cl, ALL t (mt 0..7).
   h2img[(b*128+t)*8+k, q*512 + w*8 + cl] = sum_v relu(bn(z[b,o1,t,v])) * A[b,k,c,v,w]
   v3 (merged): mh-split removed -> A-fragments (128 tanh/lane) built ONCE per
   element, in-register (no Aimg HBM round-trip like r4, no 2x tanh like r3).
   ComT[w][v] transposed+padded: tanh-loop reads 2-way (free) vs r3 flat 4-8 way.
   Stem BN finalize folded into prologue (kills the 1-block k_finalize launch). */
__global__ __launch_bounds__(256) void k_einsum_mfma(const ushort_t* __restrict__ z,
                                                     const float* __restrict__ x1,
                                                     const float* __restrict__ x2,
                                                     const float* __restrict__ ada,
                                                     const float* __restrict__ A_param,
                                                     const float* __restrict__ alphap,
                                                     const float* __restrict__ betap,
                                                     const float* __restrict__ ssum,
                                                     const float* __restrict__ ssq,
                                                     const float* __restrict__ sgamma,
                                                     const float* __restrict__ sbeta,
                                                     ushort_t* __restrict__ h2img) {
    __shared__ float ComT[64][65];   /* [w][v] padded */
    __shared__ float x1s[8][64], x2s[8][64];
    __shared__ __align__(16) ushort_t stg[16 * 520];
    __shared__ float scv8[8], shv8[8];
    int tid = threadIdx.x;
    int bid = blockIdx.x;
    int q  = bid & 3;
    int k  = (bid >> 2) & 7;
    int b  = bid >> 5;
    int wm = tid >> 6;
    int lane = tid & 63, ln = lane & 15, qq = lane >> 4;
    float alpha = alphap[0], beta = betap[0];

    /* stem BN finalize for this block's 8 channels (wave 0 only) */
    if (tid < 64) {
        int ch = tid >> 3, part = tid & 7;
        int o = k * 32 + q * 8 + ch;
        float s = 0.f, sq2 = 0.f;
        #pragma unroll
        for (int i = 0; i < 4; i++) {
            int sl = part * 4 + i;
            s   += ssum[sl * 256 + o];
            sq2 += ssq[sl * 256 + o];
        }
        s += __shfl_down(s, 4, 64);  sq2 += __shfl_down(sq2, 4, 64);
        s += __shfl_down(s, 2, 64);  sq2 += __shfl_down(sq2, 2, 64);
        s += __shfl_down(s, 1, 64);  sq2 += __shfl_down(sq2, 1, 64);
        if (part == 0) {
            float mean = s * (1.0f / (float)NBT);
            float var  = sq2 * (1.0f / (float)NBT) - mean * mean;
            float sc = sgamma[o] * rsqrtf(var + 1e-5f);
            scv8[ch] = sc;
            shv8[ch] = sbeta[o] - mean * sc;
        }
    }

    const float* Apk = A_param + (size_t)k * 4096;
    const float* adk = ada + (size_t)(b * K_ + k) * 4096;
    #pragma unroll
    for (int i = 0; i < 4; i++) {
        int e4 = tid + i * 256;          /* float4 index over [v][w] */
        int v = e4 >> 4, w4 = (e4 & 15) * 4;
        float4 ap = *(const float4*)(Apk + (size_t)e4 * 4);
        float4 ad = *(const float4*)(adk + (size_t)e4 * 4);
        ComT[w4 + 0][v] = ap.x + beta * ad.x;
        ComT[w4 + 1][v] = ap.y + beta * ad.y;
        ComT[w4 + 2][v] = ap.z + beta * ad.z;
        ComT[w4 + 3][v] = ap.w + beta * ad.w;
    }
    #pragma unroll
    for (int i = 0; i < 2; i++) {
        int e = tid + i * 256;
        int cl = e >> 6, v = e & 63;
        int o1 = k * 32 + q * 8 + cl;
        x1s[cl][v] = x1[((size_t)b * O_ + o1) * V_ + v];
        x2s[cl][v] = x2[((size_t)b * O_ + o1) * V_ + v];
    }
    __syncthreads();

    short8 bfrag[2][2][4];
    #pragma unroll
    for (int half = 0; half < 2; half++) {
        int cl = wm + half * 4;
        #pragma unroll
        for (int kk = 0; kk < 2; kk++) {
            float x1v[8];
            #pragma unroll
            for (int j = 0; j < 8; j++) x1v[j] = x1s[cl][kk * 32 + qq * 8 + j];
            #pragma unroll
            for (int nt = 0; nt < 4; nt++) {
                int w = nt * 16 + ln;
                float x2v = x2s[cl][w];
                float av[8];
                #pragma unroll
                for (int j = 0; j < 8; j++) {
                    int v = kk * 32 + qq * 8 + j;
                    float d = x1v[j] - x2v;
                    float ax = fabsf(d);
                    float e2 = __expf(-2.f * ax);
                    float th = copysignf((1.f - e2) / (1.f + e2), d);
                    av[j] = ComT[w][v] + alpha * th;
                }
                uint4 bp;
                bp.x = pack2(av[0], av[1]); bp.y = pack2(av[2], av[3]);
                bp.z = pack2(av[4], av[5]); bp.w = pack2(av[6], av[7]);
                bfrag[half][kk][nt] = __builtin_bit_cast(short8, bp);
            }
        }
    }

    int o1a = k * 32 + q * 8 + wm;
    float scv[2] = {scv8[wm], scv8[wm + 4]};
    float shv[2] = {shv8[wm], shv8[wm + 4]};
    const ushort_t* zr[2] = {z + ((size_t)b * O_ + o1a) * TN,
                             z + ((size_t)b * O_ + o1a + 4) * TN};
    size_t obase = ((size_t)(b * 128) * 8 + k) * 2048 + q * 512;

    for (int mt = 0; mt < 8; mt++) {
        f32x4 acc[2][4];
        #pragma unroll
        for (int half = 0; half < 2; half++)
            #pragma unroll
            for (int nt = 0; nt < 4; nt++) acc[half][nt] = (f32x4){0.f, 0.f, 0.f, 0.f};
        #pragma unroll
        for (int half = 0; half < 2; half++) {
            float s = scv[half], h = shv[half];
            #pragma unroll
            for (int kk = 0; kk < 2; kk++) {
                const ushort_t* src = zr[half] + (mt * 16 + ln) * 64 + kk * 32 + qq * 8;
                uint4 zv = *(const uint4*)src;
                float f0 = bf2f_lo(zv.x), f1 = bf2f_hi(zv.x);
                float f2 = bf2f_lo(zv.y), f3 = bf2f_hi(zv.y);
                float f4 = bf2f_lo(zv.z), f5 = bf2f_hi(zv.z);
                float f6 = bf2f_lo(zv.w), f7 = bf2f_hi(zv.w);
                uint4 hp;
                hp.x = pack2(fmaxf(f0 * s + h, 0.f), fmaxf(f1 * s + h, 0.f));
                hp.y = pack2(fmaxf(f2 * s + h, 0.f), fmaxf(f3 * s + h, 0.f));
                hp.z = pack2(fmaxf(f4 * s + h, 0.f), fmaxf(f5 * s + h, 0.f));
                hp.w = pack2(fmaxf(f6 * s + h, 0.f), fmaxf(f7 * s + h, 0.f));
                short8 hf = __builtin_bit_cast(short8, hp);
                #pragma unroll
                for (int nt = 0; nt < 4; nt++)
                    acc[half][nt] = __builtin_amdgcn_mfma_f32_16x16x32_bf16(hf, bfrag[half][kk][nt], acc[half][nt], 0, 0, 0);
            }
        }
        #pragma unroll
        for (int half = 0; half < 2; half++) {
            int cl = wm + half * 4;
            #pragma unroll
            for (int nt = 0; nt < 4; nt++)
                #pragma unroll
                for (int r = 0; r < 4; r++)
                    stg[(qq * 4 + r) * 520 + (nt * 16 + ln) * 8 + cl] = f2bf(acc[half][nt][r]);
        }
        __syncthreads();
        #pragma unroll
        for (int ii = 0; ii < 4; ii++) {
            int u = tid + ii * 256;
            int tl = u >> 6, off = u & 63;
            ((uint4*)(h2img + obase + (size_t)(mt * 16 + tl) * 16384))[off] =
                ((const uint4*)stg)[tl * 65 + off];
        }
        __syncthreads();
    }
}

/* out = relu(bn(u) + x); u is bf16 pre-BN, out fp32 */
__global__ __launch_bounds__(256) void k_final(const ushort_t* __restrict__ ub,
                                               const float* __restrict__ x,
                                               const float* __restrict__ scale,
                                               const float* __restrict__ shift,
                                               float* __restrict__ out) {
    size_t i4 = (size_t)blockIdx.x * 256 + threadIdx.x;
    int o = (int)((i4 >> 11) & 255);
    uint2 uv = ((const uint2*)ub)[i4];
    float4 xv = ((const float4*)x)[i4];
    float sc = scale[o], sh = shift[o];
    float4 r;
    r.x = fmaxf(bf2f_lo(uv.x) * sc + sh + xv.x, 0.f);
    r.y = fmaxf(bf2f_hi(uv.x) * sc + sh + xv.y, 0.f);
    r.z = fmaxf(bf2f_lo(uv.y) * sc + sh + xv.z, 0.f);
    r.w = fmaxf(bf2f_hi(uv.y) * sc + sh + xv.w, 0.f);
    ((float4*)out)[i4] = r;
}

extern "C" void kernel_launch(void* const* d_in, const int* in_sizes, int n_in,
                              void* d_out, int out_size, void* d_ws, size_t ws_size,
                              hipStream_t stream) {
    const float* x          = (const float*)d_in[0];
    const float* A_param    = (const float*)d_in[1];
    const float* alphap     = (const float*)d_in[2];
    const float* betap      = (const float*)d_in[3];
    const float* w1         = (const float*)d_in[4];
    const float* b1         = (const float*)d_in[5];
    const float* w2         = (const float*)d_in[6];
    const float* b2         = (const float*)d_in[7];
    const float* stem_w     = (const float*)d_in[8];
    const float* stem_b     = (const float*)d_in[9];
    const float* stem_gamma = (const float*)d_in[10];
    const float* stem_beta  = (const float*)d_in[11];
    const float* head_w     = (const float*)d_in[12];
    const float* head_b     = (const float*)d_in[13];
    const float* head_gamma = (const float*)d_in[14];
    const float* head_beta  = (const float*)d_in[15];

    float* W      = (float*)d_ws;
    float* tp     = W + OFF_TP;
    float* x1b    = W + OFF_X1;
    float* x2b    = W + OFF_X2;
    float* ssum   = W + OFF_STATS;               /* [NSL][256] */
    float* ssq    = W + OFF_STATS + NSL * 256;
    float* hsum   = W + OFF_STATS + NSL * 512;
    float* hsq    = W + OFF_STATS + NSL * 768;
    float* hscale = W + OFF_HSC;
    float* hshift = W + OFF_HSC + 256;
    float* adab   = W + OFF_ADA;
    float* uout   = (float*)d_out;

    ushort_t* xTimg  = (ushort_t*)d_out;          /* dead before k_final writes d_out */
    ushort_t* wsimg  = (ushort_t*)(W + OFF_TP);   /* tp region, after x1x2; stem+head contig */
    ushort_t* zb16   = (ushort_t*)(W + OFF_Z);    /* z bf16; u reuses it after einsum */
    ushort_t* ub16   = zb16;
    ushort_t* h2img  = (ushort_t*)(W + OFF_H2);

    /* zero tp, x1, x2, sliced stats (contiguous) */
    hipMemsetAsync(W, 0, (size_t)(OFF_STATS + NSL * 1024) * sizeof(float), stream);

    k_xpose2<<<dim3(4, 8, 16), 512, 0, stream>>>(x, xTimg, tp);
    k_x1x2a<<<dim3(16, 4, 16), 256, 0, stream>>>(tp, w1, b1, w2, b2, x1b, x2b);
    k_ada<<<8192, 64, 0, stream>>>(x1b, x2b, adab);
    k_wconv<<<dim3(16, 2), 256, 0, stream>>>(stem_w, head_w, wsimg);

    k_gemm<<<dim3(128, 1, 16), 256, 0, stream>>>(xTimg, wsimg, stem_b, zb16, ssum, ssq);

    k_einsum_mfma<<<512, 256, 0, stream>>>(zb16, x1b, x2b, adab, A_param, alphap, betap,
                                           ssum, ssq, stem_gamma, stem_beta, h2img);

    k_gemm<<<dim3(128, 1, 16), 256, 0, stream>>>(h2img, wsimg + 65536, head_b, ub16, hsum, hsq);
    k_finalize<<<1, 256, 0, stream>>>(hsum, hsq, head_gamma, head_beta, hscale, hshift);
    k_final<<<32768, 256, 0, stream>>>(ub16, x, hscale, hshift, uout);
}

// Round 6
// 482.852 us; speedup vs baseline: 1.0652x; 1.0057x over previous
//
#include <hip/hip_runtime.h>
#include <cstdint>
#include <cstddef>

#define B_ 16
#define C_ 256
#define T_ 128
#define V_ 64
#define K_ 8
#define O_ 256
#define TN 8192      /* T_*V_ */
#define NBT 131072   /* B_*T_*V_ : BN sample count */
#define NSL 32       /* stats slices (atomic contention spreader) */

typedef unsigned short ushort_t;
typedef __attribute__((ext_vector_type(8))) short short8;
typedef __attribute__((ext_vector_type(4))) float f32x4;

/* ---- workspace layout (float offsets) ---- */
#define OFF_TP     0          /* [B][C][V] 262144; reused for w-images (bf16) after x1x2 */
#define OFF_X1     262144
#define OFF_X2     524288
#define OFF_STATS  786432     /* 4 arrays x [NSL][256] = 32768 */
#define OFF_SSC    819200     /* stem scale/shift 512 (unused now) */
#define OFF_HSC    819712
#define OFF_ADA    820224     /* [B][K][V][V] 524288 -> ends 1344512 */
#define OFF_Z      1344512    /* z bf16 [B][O][TN] : 33554432 ushort = 16777216 f32; u reuses it */
#define OFF_H2     34867200   /* h2 bf16 image 33554432 ushort */

__device__ inline ushort_t f2bf(float f) {
    unsigned u = __builtin_bit_cast(unsigned, f);
    unsigned r = (u + 0x7FFFu + ((u >> 16) & 1u)) >> 16;
    return (ushort_t)r;
}
__device__ inline unsigned pack2(float a, float b) {
    return (unsigned)f2bf(a) | ((unsigned)f2bf(b) << 16);
}
__device__ inline float bf2f_lo(unsigned u) { return __builtin_bit_cast(float, u << 16); }
__device__ inline float bf2f_hi(unsigned u) { return __builtin_bit_cast(float, u & 0xFFFF0000u); }
__device__ inline void gload_lds16(const void* g, void* l) {
    __builtin_amdgcn_global_load_lds((const __attribute__((address_space(1))) unsigned int*)g,
                                     (__attribute__((address_space(3))) unsigned int*)l, 16, 0, 0);
}

/* x [b][c][t][v] fp32 -> bf16 frag image ((b*128+t)*8+cc)*2048 + q*512 + v*8 + cl
   (c = cc*32+q*8+cl); fused per-(b,c,v) mean over t.
   v4: each WAVE reads one c-row contiguously (8KB = 32t x 64v) -- fixes the HBM
   channel hotspot of v1/v2 (same-t bursts, 1.2 TB/s read ceiling). 512 threads. */
__global__ __launch_bounds__(512) void k_xpose2(const float* __restrict__ x,
                                                ushort_t* __restrict__ img,
                                                float* __restrict__ tp) {
    __shared__ float L[8 * 2048];   /* [c 8][t 32][v 64] */
    int tq = blockIdx.x;            /* 0..3 : t-range tq*32 .. +31 */
    int cg = blockIdx.y;            /* 0..7 : c-range cg*32 .. +31 */
    int b  = blockIdx.z;
    int tid  = threadIdx.x;
    int wv   = tid >> 6;            /* 0..7 : one wave per c-row */
    int lane = tid & 63;
    int t0 = tq * 32;

    float4 vreg[8];
    auto load_regs = [&](int g) {
        int c = cg * 32 + g * 8 + wv;
        const float* src = x + ((size_t)(b * C_ + c) * 128 + t0) * 64 + lane * 4;
        #pragma unroll
        for (int i = 0; i < 8; i++)
            vreg[i] = *(const float4*)(src + i * 256);
    };

    load_regs(0);
    for (int g = 0; g < 4; g++) {
        /* commit wave's c-row to LDS + per-(c,v) partial sum over 32 t */
        float4 s4 = {0.f, 0.f, 0.f, 0.f};
        #pragma unroll
        for (int i = 0; i < 8; i++) {
            *(float4*)&L[wv * 2048 + i * 256 + lane * 4] = vreg[i];
            s4.x += vreg[i].x; s4.y += vreg[i].y;
            s4.z += vreg[i].z; s4.w += vreg[i].w;
        }
        /* lanes {l, l^16, l^32, l^48} hold same v range -> reduce over t-groups */
        s4.x += __shfl_xor(s4.x, 16, 64); s4.y += __shfl_xor(s4.y, 16, 64);
        s4.z += __shfl_xor(s4.z, 16, 64); s4.w += __shfl_xor(s4.w, 16, 64);
        s4.x += __shfl_xor(s4.x, 32, 64); s4.y += __shfl_xor(s4.y, 32, 64);
        s4.z += __shfl_xor(s4.z, 32, 64); s4.w += __shfl_xor(s4.w, 32, 64);
        if (lane < 16) {
            int c = cg * 32 + g * 8 + wv;
            const float r = 1.0f / (float)T_;
            float* dst = tp + (size_t)(b * C_ + c) * V_ + lane * 4;
            atomicAdd(&dst[0], s4.x * r); atomicAdd(&dst[1], s4.y * r);
            atomicAdd(&dst[2], s4.z * r); atomicAdd(&dst[3], s4.w * r);
        }
        __syncthreads();
        if (g < 3) load_regs(g + 1);    /* next pass in flight under pack */

        /* pack: output group (cc=cg, q=g); 4 sub-steps x 8 t-rows, 512 threads */
        int v = tid & 63, tw = tid >> 6;   /* tw 0..7 */
        size_t obase = ((size_t)(b * 128 + t0) * 8 + cg) * 2048 + g * 512 + (size_t)v * 8;
        #pragma unroll
        for (int s = 0; s < 4; s++) {
            int tl = s * 8 + tw;
            const float* Lp = &L[tl * 64 + v];
            uint4 u;
            u.x = pack2(Lp[0 * 2048], Lp[1 * 2048]);
            u.y = pack2(Lp[2 * 2048], Lp[3 * 2048]);
            u.z = pack2(Lp[4 * 2048], Lp[5 * 2048]);
            u.w = pack2(Lp[6 * 2048], Lp[7 * 2048]);
            *(uint4*)(img + obase + (size_t)tl * 16384) = u;
        }
        __syncthreads();
    }
}

/* x1/x2 partials over 64-c chunk, atomic into zeroed x1/x2 */
__global__ __launch_bounds__(256) void k_x1x2a(const float* __restrict__ tp,
                                               const float* __restrict__ w1, const float* __restrict__ b1,
                                               const float* __restrict__ w2, const float* __restrict__ b2,
                                               float* __restrict__ x1, float* __restrict__ x2) {
    int og = blockIdx.x, cc = blockIdx.y, b = blockIdx.z;
    int o  = og * 16 + (threadIdx.x >> 4);
    int v4 = threadIdx.x & 15;
    const float4* ptp = (const float4*)(tp + (size_t)b * C_ * V_) + v4;
    float4 s1 = {0.f,0.f,0.f,0.f}, s2 = {0.f,0.f,0.f,0.f};
    int c0 = cc * 64;
    for (int c = c0; c < c0 + 64; c++) {
        float4 tv = ptp[c * 16];
        float wa = w1[o * C_ + c];
        float wb = w2[o * C_ + c];
        s1.x += tv.x * wa; s1.y += tv.y * wa; s1.z += tv.z * wa; s1.w += tv.w * wa;
        s2.x += tv.x * wb; s2.y += tv.y * wb; s2.z += tv.z * wb; s2.w += tv.w * wb;
    }
    if (cc == 0) {
        float bv1 = b1[o], bv2 = b2[o];
        s1.x += bv1; s1.y += bv1; s1.z += bv1; s1.w += bv1;
        s2.x += bv2; s2.y += bv2; s2.z += bv2; s2.w += bv2;
    }
    float* p1 = x1 + (size_t)(b * O_ + o) * V_ + v4 * 4;
    float* p2 = x2 + (size_t)(b * O_ + o) * V_ + v4 * 4;
    atomicAdd(&p1[0], s1.x); atomicAdd(&p1[1], s1.y); atomicAdd(&p1[2], s1.z); atomicAdd(&p1[3], s1.w);
    atomicAdd(&p2[0], s2.x); atomicAdd(&p2[1], s2.y); atomicAdd(&p2[2], s2.z); atomicAdd(&p2[3], s2.w);
}

/* ada[b,k,v,w] = softmax_v( sum_c x1[b,k,c,v]*x2[b,k,c,w] ) one wave per (b,k,w) */
__global__ __launch_bounds__(64) void k_ada(const float* __restrict__ x1,
                                            const float* __restrict__ x2,
                                            float* __restrict__ ada) {
    int bid = blockIdx.x;
    int w = bid & 63;
    int k = (bid >> 6) & 7;
    int b = bid >> 9;
    int v = threadIdx.x;
    const float* p1 = x1 + ((size_t)b * O_ + k * 32) * V_;
    const float* p2 = x2 + ((size_t)b * O_ + k * 32) * V_;
    float s = 0.f;
    #pragma unroll
    for (int c = 0; c < 32; c++) s += p1[c * V_ + v] * p2[c * V_ + w];
    float m = s;
    #pragma unroll
    for (int off = 32; off >= 1; off >>= 1) m = fmaxf(m, __shfl_xor(m, off, 64));
    float e = __expf(s - m);
    float sum = e;
    #pragma unroll
    for (int off = 32; off >= 1; off >>= 1) sum += __shfl_xor(sum, off, 64);
    ada[((size_t)(b * K_ + k) * V_ + v) * V_ + w] = e / sum;
}

/* w[256][256] fp32 -> bf16 image: [cc 8][q 4][ol 256][cl 8]; blockIdx.y picks stem/head */
__global__ __launch_bounds__(256) void k_wconv(const float* __restrict__ ws,
                                               const float* __restrict__ wh,
                                               ushort_t* __restrict__ img) {
    const float* w = blockIdx.y ? wh : ws;
    ushort_t* dst = img + (size_t)blockIdx.y * 65536;
    int flat = blockIdx.x * 256 + threadIdx.x;
    #pragma unroll
    for (int g2 = 0; g2 < 2; g2++) {
        int gi = flat * 2 + g2;
        int cc = gi >> 10;
        int q  = (gi >> 8) & 3;
        int ol = gi & 255;
        int c0 = cc * 32 + q * 8;
        const float* src = w + (size_t)ol * C_ + c0;
        float4 f0 = *(const float4*)src;
        float4 f1 = *(const float4*)(src + 4);
        uint4 u;
        u.x = pack2(f0.x, f0.y); u.y = pack2(f0.z, f0.w);
        u.z = pack2(f1.x, f1.y); u.w = pack2(f1.z, f1.w);
        *(uint4*)(dst + (size_t)gi * 8) = u;
    }
}

/* out[b][o][n] = bf16( sum_c W[o][c] X[b][n][c] + bias[o] ); fused exact-fp32 BN stats.
   v2: double-buffered LDS staging -- gload_lds(cc+1) issued BEFORE consuming cc, so
   the stage latency hides under wimg-loads+MFMA; one __syncthreads per K-step (was 2,
   with the first draining vmcnt(0) right after issue = full latency exposed). */
__global__ __launch_bounds__(256) void k_gemm(const ushort_t* __restrict__ ximg,
                                              const ushort_t* __restrict__ wimg,
                                              const float* __restrict__ bias,
                                              ushort_t* __restrict__ out,
                                              float* __restrict__ psum,
                                              float* __restrict__ psumsq) {
    __shared__ __align__(16) ushort_t sh[2][2048];
    int tid = threadIdx.x;
    int nblk = blockIdx.x, b = blockIdx.z;
    int wm = tid >> 6;
    int lane = tid & 63, ln = lane & 15, q = lane >> 4;
    f32x4 acc[4][4];
    #pragma unroll
    for (int mt = 0; mt < 4; mt++)
        #pragma unroll
        for (int nt = 0; nt < 4; nt++) acc[mt][nt] = (f32x4){0.f, 0.f, 0.f, 0.f};
    const ushort_t* xbase = ximg + ((size_t)(b * 128 + nblk) * 8) * 2048;
    gload_lds16(xbase + wm * 512 + lane * 8, &sh[0][wm * 512]);
    __syncthreads();
    for (int cc = 0; cc < 8; cc++) {
        int cur = cc & 1;
        if (cc < 7)
            gload_lds16(xbase + (size_t)(cc + 1) * 2048 + wm * 512 + lane * 8,
                        &sh[cur ^ 1][wm * 512]);
        short8 a[4], bb[4];
        const ushort_t* wc = wimg + (size_t)cc * 8192 + q * 2048;
        #pragma unroll
        for (int mt = 0; mt < 4; mt++)
            a[mt] = *(const short8*)(wc + (wm * 64 + mt * 16 + ln) * 8);
        #pragma unroll
        for (int nt = 0; nt < 4; nt++)
            bb[nt] = *(const short8*)&sh[cur][q * 512 + (nt * 16 + ln) * 8];
        #pragma unroll
        for (int mt = 0; mt < 4; mt++)
            #pragma unroll
            for (int nt = 0; nt < 4; nt++)
                acc[mt][nt] = __builtin_amdgcn_mfma_f32_16x16x32_bf16(a[mt], bb[nt], acc[mt][nt], 0, 0, 0);
        __syncthreads();   /* drains vmcnt(0): next-stage landed; reads of cur done */
    }
    int n_base = nblk * 64;
    int slice = (nblk ^ (b << 3)) & (NSL - 1);
    #pragma unroll
    for (int mt = 0; mt < 4; mt++) {
        int o0 = wm * 64 + mt * 16 + q * 4;
        #pragma unroll
        for (int r = 0; r < 4; r++) {
            float bv = bias[o0 + r];
            float v0 = acc[mt][0][r] + bv, v1 = acc[mt][1][r] + bv;
            float v2 = acc[mt][2][r] + bv, v3 = acc[mt][3][r] + bv;
            ushort_t* orow = out + ((size_t)(b * O_ + o0 + r)) * TN + n_base + ln;
            orow[0] = f2bf(v0); orow[16] = f2bf(v1); orow[32] = f2bf(v2); orow[48] = f2bf(v3);
            float s  = v0 + v1 + v2 + v3;
            float sq = v0 * v0 + v1 * v1 + v2 * v2 + v3 * v3;
            #pragma unroll
            for (int off = 1; off <= 8; off <<= 1) {
                s  += __shfl_xor(s,  off, 64);
                sq += __shfl_xor(sq, off, 64);
            }
            if (ln == 0) {
                atomicAdd(&psum[slice * 256 + o0 + r],   s);
                atomicAdd(&psumsq[slice * 256 + o0 + r], sq);
            }
        }
    }
}

__global__ void k_finalize(const float* __restrict__ psum, const float* __restrict__ psumsq,
                           const float* __restrict__ gamma, const float* __restrict__ betap,
                           float* __restrict__ scale, float* __restrict__ shift) {
    int o = threadIdx.x;
    float s = 0.f, sq = 0.f;
    #pragma unroll
    for (int sl = 0; sl < NSL; sl++) {
        s  += psum[sl * 256 + o];
        sq += psumsq[sl * 256 + o];
    }
    float mean = s  * (1.0f / (float)NBT);
    float var  = sq * (1.0f / (float)NBT) - mean * mean;
    float sc = gamma[o] * rsqrtf(var + 1e-5f);
    scale[o] = sc;
    shift[o] = betap[o] - mean * sc;
}

/* MFMA einsum: per block (b,k,q): 8 channels o1=k*32+q*8+cl, ALL t (mt 0..7).
   v4: register-prefetch of z(mt+1) issued before mt's BN/pack/MFMA/stg phase --
   z-load latency hides under compute + the two stg barriers (was fully exposed
   at the top of each mt step). Statically-indexed double buffer (no dyn idx). */
__global__ __launch_bounds__(256) void k_einsum_mfma(const ushort_t* __restrict__ z,
                                                     const float* __restrict__ x1,
                                                     const float* __restrict__ x2,
                                                     const float* __restrict__ ada,
                                                     const float* __restrict__ A_param,
                                                     const float* __restrict__ alphap,
                                                     const float* __restrict__ betap,
                                                     const float* __restrict__ ssum,
                                                     const float* __restrict__ ssq,
                                                     const float* __restrict__ sgamma,
                                                     const float* __restrict__ sbeta,
                                                     ushort_t* __restrict__ h2img) {
    __shared__ float ComT[64][65];   /* [w][v] padded */
    __shared__ float x1s[8][64], x2s[8][64];
    __shared__ __align__(16) ushort_t stg[16 * 520];
    __shared__ float scv8[8], shv8[8];
    int tid = threadIdx.x;
    int bid = blockIdx.x;
    int q  = bid & 3;
    int k  = (bid >> 2) & 7;
    int b  = bid >> 5;
    int wm = tid >> 6;
    int lane = tid & 63, ln = lane & 15, qq = lane >> 4;
    float alpha = alphap[0], beta = betap[0];

    /* stem BN finalize for this block's 8 channels (wave 0 only) */
    if (tid < 64) {
        int ch = tid >> 3, part = tid & 7;
        int o = k * 32 + q * 8 + ch;
        float s = 0.f, sq2 = 0.f;
        #pragma unroll
        for (int i = 0; i < 4; i++) {
            int sl = part * 4 + i;
            s   += ssum[sl * 256 + o];
            sq2 += ssq[sl * 256 + o];
        }
        s += __shfl_down(s, 4, 64);  sq2 += __shfl_down(sq2, 4, 64);
        s += __shfl_down(s, 2, 64);  sq2 += __shfl_down(sq2, 2, 64);
        s += __shfl_down(s, 1, 64);  sq2 += __shfl_down(sq2, 1, 64);
        if (part == 0) {
            float mean = s * (1.0f / (float)NBT);
            float var  = sq2 * (1.0f / (float)NBT) - mean * mean;
            float sc = sgamma[o] * rsqrtf(var + 1e-5f);
            scv8[ch] = sc;
            shv8[ch] = sbeta[o] - mean * sc;
        }
    }

    const float* Apk = A_param + (size_t)k * 4096;
    const float* adk = ada + (size_t)(b * K_ + k) * 4096;
    #pragma unroll
    for (int i = 0; i < 4; i++) {
        int e4 = tid + i * 256;          /* float4 index over [v][w] */
        int v = e4 >> 4, w4 = (e4 & 15) * 4;
        float4 ap = *(const float4*)(Apk + (size_t)e4 * 4);
        float4 ad = *(const float4*)(adk + (size_t)e4 * 4);
        ComT[w4 + 0][v] = ap.x + beta * ad.x;
        ComT[w4 + 1][v] = ap.y + beta * ad.y;
        ComT[w4 + 2][v] = ap.z + beta * ad.z;
        ComT[w4 + 3][v] = ap.w + beta * ad.w;
    }
    #pragma unroll
    for (int i = 0; i < 2; i++) {
        int e = tid + i * 256;
        int cl = e >> 6, v = e & 63;
        int o1 = k * 32 + q * 8 + cl;
        x1s[cl][v] = x1[((size_t)b * O_ + o1) * V_ + v];
        x2s[cl][v] = x2[((size_t)b * O_ + o1) * V_ + v];
    }
    __syncthreads();

    short8 bfrag[2][2][4];
    #pragma unroll
    for (int half = 0; half < 2; half++) {
        int cl = wm + half * 4;
        #pragma unroll
        for (int kk = 0; kk < 2; kk++) {
            float x1v[8];
            #pragma unroll
            for (int j = 0; j < 8; j++) x1v[j] = x1s[cl][kk * 32 + qq * 8 + j];
            #pragma unroll
            for (int nt = 0; nt < 4; nt++) {
                int w = nt * 16 + ln;
                float x2v = x2s[cl][w];
                float av[8];
                #pragma unroll
                for (int j = 0; j < 8; j++) {
                    int v = kk * 32 + qq * 8 + j;
                    float d = x1v[j] - x2v;
                    float ax = fabsf(d);
                    float e2 = __expf(-2.f * ax);
                    float th = copysignf((1.f - e2) / (1.f + e2), d);
                    av[j] = ComT[w][v] + alpha * th;
                }
                uint4 bp;
                bp.x = pack2(av[0], av[1]); bp.y = pack2(av[2], av[3]);
                bp.z = pack2(av[4], av[5]); bp.w = pack2(av[6], av[7]);
                bfrag[half][kk][nt] = __builtin_bit_cast(short8, bp);
            }
        }
    }

    int o1a = k * 32 + q * 8 + wm;
    float scv[2] = {scv8[wm], scv8[wm + 4]};
    float shv[2] = {shv8[wm], shv8[wm + 4]};
    const ushort_t* zr[2] = {z + ((size_t)b * O_ + o1a) * TN,
                             z + ((size_t)b * O_ + o1a + 4) * TN};
    size_t obase = ((size_t)(b * 128) * 8 + k) * 2048 + q * 512;

    uint4 zc[2][2];
    #pragma unroll
    for (int half = 0; half < 2; half++)
        #pragma unroll
        for (int kk = 0; kk < 2; kk++)
            zc[half][kk] = *(const uint4*)(zr[half] + (0 * 16 + ln) * 64 + kk * 32 + qq * 8);

    for (int mt = 0; mt < 8; mt++) {
        uint4 zn[2][2];
        if (mt < 7) {
            #pragma unroll
            for (int half = 0; half < 2; half++)
                #pragma unroll
                for (int kk = 0; kk < 2; kk++)
                    zn[half][kk] = *(const uint4*)(zr[half] + ((mt + 1) * 16 + ln) * 64 + kk * 32 + qq * 8);
        }
        f32x4 acc[2][4];
        #pragma unroll
        for (int half = 0; half < 2; half++)
            #pragma unroll
            for (int nt = 0; nt < 4; nt++) acc[half][nt] = (f32x4){0.f, 0.f, 0.f, 0.f};
        #pragma unroll
        for (int half = 0; half < 2; half++) {
            float s = scv[half], h = shv[half];
            #pragma unroll
            for (int kk = 0; kk < 2; kk++) {
                uint4 zv = zc[half][kk];
                float f0 = bf2f_lo(zv.x), f1 = bf2f_hi(zv.x);
                float f2 = bf2f_lo(zv.y), f3 = bf2f_hi(zv.y);
                float f4 = bf2f_lo(zv.z), f5 = bf2f_hi(zv.z);
                float f6 = bf2f_lo(zv.w), f7 = bf2f_hi(zv.w);
                uint4 hp;
                hp.x = pack2(fmaxf(f0 * s + h, 0.f), fmaxf(f1 * s + h, 0.f));
                hp.y = pack2(fmaxf(f2 * s + h, 0.f), fmaxf(f3 * s + h, 0.f));
                hp.z = pack2(fmaxf(f4 * s + h, 0.f), fmaxf(f5 * s + h, 0.f));
                hp.w = pack2(fmaxf(f6 * s + h, 0.f), fmaxf(f7 * s + h, 0.f));
                short8 hf = __builtin_bit_cast(short8, hp);
                #pragma unroll
                for (int nt = 0; nt < 4; nt++)
                    acc[half][nt] = __builtin_amdgcn_mfma_f32_16x16x32_bf16(hf, bfrag[half][kk][nt], acc[half][nt], 0, 0, 0);
            }
        }
        #pragma unroll
        for (int half = 0; half < 2; half++) {
            int cl = wm + half * 4;
            #pragma unroll
            for (int nt = 0; nt < 4; nt++)
                #pragma unroll
                for (int r = 0; r < 4; r++)
                    stg[(qq * 4 + r) * 520 + (nt * 16 + ln) * 8 + cl] = f2bf(acc[half][nt][r]);
        }
        __syncthreads();
        #pragma unroll
        for (int ii = 0; ii < 4; ii++) {
            int u = tid + ii * 256;
            int tl = u >> 6, off = u & 63;
            ((uint4*)(h2img + obase + (size_t)(mt * 16 + tl) * 16384))[off] =
                ((const uint4*)stg)[tl * 65 + off];
        }
        __syncthreads();
        if (mt < 7) {
            #pragma unroll
            for (int half = 0; half < 2; half++)
                #pragma unroll
                for (int kk = 0; kk < 2; kk++)
                    zc[half][kk] = zn[half][kk];
        }
    }
}

/* out = relu(bn(u) + x); u is bf16 pre-BN, out fp32 */
__global__ __launch_bounds__(256) void k_final(const ushort_t* __restrict__ ub,
                                               const float* __restrict__ x,
                                               const float* __restrict__ scale,
                                               const float* __restrict__ shift,
                                               float* __restrict__ out) {
    size_t i4 = (size_t)blockIdx.x * 256 + threadIdx.x;
    int o = (int)((i4 >> 11) & 255);
    uint2 uv = ((const uint2*)ub)[i4];
    float4 xv = ((const float4*)x)[i4];
    float sc = scale[o], sh = shift[o];
    float4 r;
    r.x = fmaxf(bf2f_lo(uv.x) * sc + sh + xv.x, 0.f);
    r.y = fmaxf(bf2f_hi(uv.x) * sc + sh + xv.y, 0.f);
    r.z = fmaxf(bf2f_lo(uv.y) * sc + sh + xv.z, 0.f);
    r.w = fmaxf(bf2f_hi(uv.y) * sc + sh + xv.w, 0.f);
    ((float4*)out)[i4] = r;
}

extern "C" void kernel_launch(void* const* d_in, const int* in_sizes, int n_in,
                              void* d_out, int out_size, void* d_ws, size_t ws_size,
                              hipStream_t stream) {
    const float* x          = (const float*)d_in[0];
    const float* A_param    = (const float*)d_in[1];
    const float* alphap     = (const float*)d_in[2];
    const float* betap      = (const float*)d_in[3];
    const float* w1         = (const float*)d_in[4];
    const float* b1         = (const float*)d_in[5];
    const float* w2         = (const float*)d_in[6];
    const float* b2         = (const float*)d_in[7];
    const float* stem_w     = (const float*)d_in[8];
    const float* stem_b     = (const float*)d_in[9];
    const float* stem_gamma = (const float*)d_in[10];
    const float* stem_beta  = (const float*)d_in[11];
    const float* head_w     = (const float*)d_in[12];
    const float* head_b     = (const float*)d_in[13];
    const float* head_gamma = (const float*)d_in[14];
    const float* head_beta  = (const float*)d_in[15];

    float* W      = (float*)d_ws;
    float* tp     = W + OFF_TP;
    float* x1b    = W + OFF_X1;
    float* x2b    = W + OFF_X2;
    float* ssum   = W + OFF_STATS;               /* [NSL][256] */
    float* ssq    = W + OFF_STATS + NSL * 256;
    float* hsum   = W + OFF_STATS + NSL * 512;
    float* hsq    = W + OFF_STATS + NSL * 768;
    float* hscale = W + OFF_HSC;
    float* hshift = W + OFF_HSC + 256;
    float* adab   = W + OFF_ADA;
    float* uout   = (float*)d_out;

    ushort_t* xTimg  = (ushort_t*)d_out;          /* dead before k_final writes d_out */
    ushort_t* wsimg  = (ushort_t*)(W + OFF_TP);   /* tp region, after x1x2; stem+head contig */
    ushort_t* zb16   = (ushort_t*)(W + OFF_Z);    /* z bf16; u reuses it after einsum */
    ushort_t* ub16   = zb16;
    ushort_t* h2img  = (ushort_t*)(W + OFF_H2);

    /* zero tp, x1, x2, sliced stats (contiguous) */
    hipMemsetAsync(W, 0, (size_t)(OFF_STATS + NSL * 1024) * sizeof(float), stream);

    k_xpose2<<<dim3(4, 8, 16), 512, 0, stream>>>(x, xTimg, tp);
    k_x1x2a<<<dim3(16, 4, 16), 256, 0, stream>>>(tp, w1, b1, w2, b2, x1b, x2b);
    k_ada<<<8192, 64, 0, stream>>>(x1b, x2b, adab);
    k_wconv<<<dim3(16, 2), 256, 0, stream>>>(stem_w, head_w, wsimg);

    k_gemm<<<dim3(128, 1, 16), 256, 0, stream>>>(xTimg, wsimg, stem_b, zb16, ssum, ssq);

    k_einsum_mfma<<<512, 256, 0, stream>>>(zb16, x1b, x2b, adab, A_param, alphap, betap,
                                           ssum, ssq, stem_gamma, stem_beta, h2img);

    k_gemm<<<dim3(128, 1, 16), 256, 0, stream>>>(h2img, wsimg + 65536, head_b, ub16, hsum, hsq);
    k_finalize<<<1, 256, 0, stream>>>(hsum, hsq, head_gamma, head_beta, hscale, hshift);
    k_final<<<32768, 256, 0, stream>>>(ub16, x, hscale, hshift, uout);
}

// Round 8
// 475.845 us; speedup vs baseline: 1.0809x; 1.0147x over previous
//
#include <hip/hip_runtime.h>
#include <cstdint>
#include <cstddef>

#define B_ 16
#define C_ 256
#define T_ 128
#define V_ 64
#define K_ 8
#define O_ 256
#define TN 8192      /* T_*V_ */
#define NBT 131072   /* B_*T_*V_ : BN sample count */
#define NSL 32       /* stats slices (atomic contention spreader) */

typedef unsigned short ushort_t;
typedef __attribute__((ext_vector_type(8))) short short8;
typedef __attribute__((ext_vector_type(4))) float f32x4;

/* ---- workspace layout (float offsets) ---- */
#define OFF_TP     0          /* [B][C][V] 262144 */
#define OFF_X1     262144
#define OFF_X2     524288
#define OFF_STATS  786432     /* 4 arrays x [NSL][256] = 32768 */
#define OFF_WIMG   820224     /* w images (bf16): 2 x 65536 ushort = 65536 f32 (old ada region) */
#define OFF_Z      1344512    /* z bf16 [B][O][TN] : 33554432 ushort; u reuses it */
#define OFF_H2     34867200   /* h2 bf16 image 33554432 ushort */

__device__ inline ushort_t f2bf(float f) {
    unsigned u = __builtin_bit_cast(unsigned, f);
    unsigned r = (u + 0x7FFFu + ((u >> 16) & 1u)) >> 16;
    return (ushort_t)r;
}
__device__ inline unsigned pack2(float a, float b) {
    return (unsigned)f2bf(a) | ((unsigned)f2bf(b) << 16);
}
__device__ inline float bf2f_lo(unsigned u) { return __builtin_bit_cast(float, u << 16); }
__device__ inline float bf2f_hi(unsigned u) { return __builtin_bit_cast(float, u & 0xFFFF0000u); }
__device__ inline void gload_lds16(const void* g, void* l) {
    __builtin_amdgcn_global_load_lds((const __attribute__((address_space(1))) unsigned int*)g,
                                     (__attribute__((address_space(3))) unsigned int*)l, 16, 0, 0);
}

/* x [b][c][t][v] fp32 -> bf16 frag image; fused per-(b,c,v) mean over t.
   v5: wconv folded in as blockIdx.z==16 slice (independent work, saves a launch).
   Wave reads one c-row contiguously (8KB) -- the r3 channel-hotspot fix. */
__global__ __launch_bounds__(512) void k_xpose2(const float* __restrict__ x,
                                                ushort_t* __restrict__ img,
                                                float* __restrict__ tp,
                                                const float* __restrict__ stem_w,
                                                const float* __restrict__ head_w,
                                                ushort_t* __restrict__ wimg) {
    __shared__ float L[8 * 2048];   /* [c 8][t 32][v 64] */
    int tq = blockIdx.x;            /* 0..3 */
    int cg = blockIdx.y;            /* 0..7 */
    int b  = blockIdx.z;            /* 0..15 xpose; 16 -> wconv slice */
    int tid  = threadIdx.x;

    if (b == 16) {
        /* w[256][256] fp32 -> bf16 image [cc 8][q 4][ol 256][cl 8]; m=0 stem, m=1 head */
        int flat = cg * 4 + tq;                 /* 0..31 */
        int gi2 = flat * 512 + tid;             /* 0..16383 */
        int m  = gi2 >> 13;
        int gi = gi2 & 8191;
        const float* w = m ? head_w : stem_w;
        int cc = gi >> 10;
        int q  = (gi >> 8) & 3;
        int ol = gi & 255;
        int c0 = cc * 32 + q * 8;
        const float* src = w + (size_t)ol * C_ + c0;
        float4 f0 = *(const float4*)src;
        float4 f1 = *(const float4*)(src + 4);
        uint4 u;
        u.x = pack2(f0.x, f0.y); u.y = pack2(f0.z, f0.w);
        u.z = pack2(f1.x, f1.y); u.w = pack2(f1.z, f1.w);
        *(uint4*)(wimg + (size_t)m * 65536 + (size_t)gi * 8) = u;
        return;
    }

    int wv   = tid >> 6;            /* 0..7 : one wave per c-row */
    int lane = tid & 63;
    int t0 = tq * 32;

    float4 vreg[8];
    auto load_regs = [&](int g) {
        int c = cg * 32 + g * 8 + wv;
        const float* src = x + ((size_t)(b * C_ + c) * 128 + t0) * 64 + lane * 4;
        #pragma unroll
        for (int i = 0; i < 8; i++)
            vreg[i] = *(const float4*)(src + i * 256);
    };

    load_regs(0);
    for (int g = 0; g < 4; g++) {
        float4 s4 = {0.f, 0.f, 0.f, 0.f};
        #pragma unroll
        for (int i = 0; i < 8; i++) {
            *(float4*)&L[wv * 2048 + i * 256 + lane * 4] = vreg[i];
            s4.x += vreg[i].x; s4.y += vreg[i].y;
            s4.z += vreg[i].z; s4.w += vreg[i].w;
        }
        s4.x += __shfl_xor(s4.x, 16, 64); s4.y += __shfl_xor(s4.y, 16, 64);
        s4.z += __shfl_xor(s4.z, 16, 64); s4.w += __shfl_xor(s4.w, 16, 64);
        s4.x += __shfl_xor(s4.x, 32, 64); s4.y += __shfl_xor(s4.y, 32, 64);
        s4.z += __shfl_xor(s4.z, 32, 64); s4.w += __shfl_xor(s4.w, 32, 64);
        if (lane < 16) {
            int c = cg * 32 + g * 8 + wv;
            const float r = 1.0f / (float)T_;
            float* dst = tp + (size_t)(b * C_ + c) * V_ + lane * 4;
            atomicAdd(&dst[0], s4.x * r); atomicAdd(&dst[1], s4.y * r);
            atomicAdd(&dst[2], s4.z * r); atomicAdd(&dst[3], s4.w * r);
        }
        __syncthreads();
        if (g < 3) load_regs(g + 1);

        int v = tid & 63, tw = tid >> 6;
        size_t obase = ((size_t)(b * 128 + t0) * 8 + cg) * 2048 + g * 512 + (size_t)v * 8;
        #pragma unroll
        for (int s = 0; s < 4; s++) {
            int tl = s * 8 + tw;
            const float* Lp = &L[tl * 64 + v];
            uint4 u;
            u.x = pack2(Lp[0 * 2048], Lp[1 * 2048]);
            u.y = pack2(Lp[2 * 2048], Lp[3 * 2048]);
            u.z = pack2(Lp[4 * 2048], Lp[5 * 2048]);
            u.w = pack2(Lp[6 * 2048], Lp[7 * 2048]);
            *(uint4*)(img + obase + (size_t)tl * 16384) = u;
        }
        __syncthreads();
    }
}

/* x1/x2 partials over 64-c chunk, atomic into zeroed x1/x2 */
__global__ __launch_bounds__(256) void k_x1x2a(const float* __restrict__ tp,
                                               const float* __restrict__ w1, const float* __restrict__ b1,
                                               const float* __restrict__ w2, const float* __restrict__ b2,
                                               float* __restrict__ x1, float* __restrict__ x2) {
    int og = blockIdx.x, cc = blockIdx.y, b = blockIdx.z;
    int o  = og * 16 + (threadIdx.x >> 4);
    int v4 = threadIdx.x & 15;
    const float4* ptp = (const float4*)(tp + (size_t)b * C_ * V_) + v4;
    float4 s1 = {0.f,0.f,0.f,0.f}, s2 = {0.f,0.f,0.f,0.f};
    int c0 = cc * 64;
    for (int c = c0; c < c0 + 64; c++) {
        float4 tv = ptp[c * 16];
        float wa = w1[o * C_ + c];
        float wb = w2[o * C_ + c];
        s1.x += tv.x * wa; s1.y += tv.y * wa; s1.z += tv.z * wa; s1.w += tv.w * wa;
        s2.x += tv.x * wb; s2.y += tv.y * wb; s2.z += tv.z * wb; s2.w += tv.w * wb;
    }
    if (cc == 0) {
        float bv1 = b1[o], bv2 = b2[o];
        s1.x += bv1; s1.y += bv1; s1.z += bv1; s1.w += bv1;
        s2.x += bv2; s2.y += bv2; s2.z += bv2; s2.w += bv2;
    }
    float* p1 = x1 + (size_t)(b * O_ + o) * V_ + v4 * 4;
    float* p2 = x2 + (size_t)(b * O_ + o) * V_ + v4 * 4;
    atomicAdd(&p1[0], s1.x); atomicAdd(&p1[1], s1.y); atomicAdd(&p1[2], s1.z); atomicAdd(&p1[3], s1.w);
    atomicAdd(&p2[0], s2.x); atomicAdd(&p2[1], s2.y); atomicAdd(&p2[2], s2.z); atomicAdd(&p2[3], s2.w);
}

/* out[b][o][n] = bf16( sum_c W[o][c] X[b][n][c] + bias[o] ); fused exact-fp32 BN stats.
   v3: output staged through LDS and flushed as 16B-coalesced rows (old path: 2-byte
   scalar stores, 32B/row granules on 16KB-strided rows -> wasted HBM write granules). */
__global__ __launch_bounds__(256) void k_gemm(const ushort_t* __restrict__ ximg,
                                              const ushort_t* __restrict__ wimg,
                                              const float* __restrict__ bias,
                                              ushort_t* __restrict__ out,
                                              float* __restrict__ psum,
                                              float* __restrict__ psumsq) {
    __shared__ __align__(16) ushort_t sh[2][2048];
    __shared__ __align__(16) ushort_t stg[64 * 72];   /* pitch 72: 16B-aligned rows */
    int tid = threadIdx.x;
    int nblk = blockIdx.x, b = blockIdx.z;
    int wm = tid >> 6;
    int lane = tid & 63, ln = lane & 15, q = lane >> 4;
    f32x4 acc[4][4];
    #pragma unroll
    for (int mt = 0; mt < 4; mt++)
        #pragma unroll
        for (int nt = 0; nt < 4; nt++) acc[mt][nt] = (f32x4){0.f, 0.f, 0.f, 0.f};
    const ushort_t* xbase = ximg + ((size_t)(b * 128 + nblk) * 8) * 2048;
    gload_lds16(xbase + wm * 512 + lane * 8, &sh[0][wm * 512]);
    __syncthreads();
    for (int cc = 0; cc < 8; cc++) {
        int cur = cc & 1;
        if (cc < 7)
            gload_lds16(xbase + (size_t)(cc + 1) * 2048 + wm * 512 + lane * 8,
                        &sh[cur ^ 1][wm * 512]);
        short8 a[4], bb[4];
        const ushort_t* wc = wimg + (size_t)cc * 8192 + q * 2048;
        #pragma unroll
        for (int mt = 0; mt < 4; mt++)
            a[mt] = *(const short8*)(wc + (wm * 64 + mt * 16 + ln) * 8);
        #pragma unroll
        for (int nt = 0; nt < 4; nt++)
            bb[nt] = *(const short8*)&sh[cur][q * 512 + (nt * 16 + ln) * 8];
        #pragma unroll
        for (int mt = 0; mt < 4; mt++)
            #pragma unroll
            for (int nt = 0; nt < 4; nt++)
                acc[mt][nt] = __builtin_amdgcn_mfma_f32_16x16x32_bf16(a[mt], bb[nt], acc[mt][nt], 0, 0, 0);
        __syncthreads();
    }
    int n_base = nblk * 64;
    int slice = (nblk ^ (b << 3)) & (NSL - 1);
    #pragma unroll
    for (int mt = 0; mt < 4; mt++) {
        #pragma unroll
        for (int r = 0; r < 4; r++) {
            int o0 = wm * 64 + mt * 16 + q * 4;
            float bv = bias[o0 + r];
            float v0 = acc[mt][0][r] + bv, v1 = acc[mt][1][r] + bv;
            float v2 = acc[mt][2][r] + bv, v3 = acc[mt][3][r] + bv;
            int row = wm * 16 + q * 4 + r;
            stg[row * 72 +  0 + ln] = f2bf(v0);
            stg[row * 72 + 16 + ln] = f2bf(v1);
            stg[row * 72 + 32 + ln] = f2bf(v2);
            stg[row * 72 + 48 + ln] = f2bf(v3);
            float s  = v0 + v1 + v2 + v3;
            float sq = v0 * v0 + v1 * v1 + v2 * v2 + v3 * v3;
            #pragma unroll
            for (int off = 1; off <= 8; off <<= 1) {
                s  += __shfl_xor(s,  off, 64);
                sq += __shfl_xor(sq, off, 64);
            }
            if (ln == 0) {
                atomicAdd(&psum[slice * 256 + o0 + r],   s);
                atomicAdd(&psumsq[slice * 256 + o0 + r], sq);
            }
        }
        __syncthreads();
        #pragma unroll
        for (int ii = 0; ii < 2; ii++) {
            int unit = tid + ii * 256;               /* 512 units of 16B */
            int row = unit >> 3, c8 = (unit & 7) * 8;
            int o = (row >> 4) * 64 + mt * 16 + (row & 15);
            *(uint4*)(out + (size_t)(b * O_ + o) * TN + n_base + c8) =
                *(const uint4*)&stg[row * 72 + c8];
        }
        __syncthreads();
    }
}

/* MFMA einsum, per block (b,k,q): 8 channels o1=k*32+q*8+cl, ALL t.
   v5: ada (scores+softmax over v) computed IN-BLOCK from x1k/x2k (kills the 8192-block
   k_ada launch + its global round-trip; 4x-redundant over q but only ~0.5us chip-wide).
   Stem BN finalize in prologue. z(mt+1) register prefetch. */
__global__ __launch_bounds__(256) void k_einsum_mfma(const ushort_t* __restrict__ z,
                                                     const float* __restrict__ x1,
                                                     const float* __restrict__ x2,
                                                     const float* __restrict__ A_param,
                                                     const float* __restrict__ alphap,
                                                     const float* __restrict__ betap,
                                                     const float* __restrict__ ssum,
                                                     const float* __restrict__ ssq,
                                                     const float* __restrict__ sgamma,
                                                     const float* __restrict__ sbeta,
                                                     ushort_t* __restrict__ h2img) {
    __shared__ float ComT[64][65];   /* [w][v] padded */
    __shared__ float x1k[32][64], x2k[32][64];
    __shared__ float adaS[64][65];   /* [v][w] padded */
    __shared__ __align__(16) ushort_t stg[16 * 520];
    __shared__ float scv8[8], shv8[8];
    int tid = threadIdx.x;
    int bid = blockIdx.x;
    int q  = bid & 3;
    int k  = (bid >> 2) & 7;
    int b  = bid >> 5;
    int wm = tid >> 6;
    int lane = tid & 63, ln = lane & 15, qq = lane >> 4;
    float alpha = alphap[0], beta = betap[0];

    /* stem BN finalize for this block's 8 channels (wave 0 only) */
    if (tid < 64) {
        int ch = tid >> 3, part = tid & 7;
        int o = k * 32 + q * 8 + ch;
        float s = 0.f, sq2 = 0.f;
        #pragma unroll
        for (int i = 0; i < 4; i++) {
            int sl = part * 4 + i;
            s   += ssum[sl * 256 + o];
            sq2 += ssq[sl * 256 + o];
        }
        s += __shfl_down(s, 4, 64);  sq2 += __shfl_down(sq2, 4, 64);
        s += __shfl_down(s, 2, 64);  sq2 += __shfl_down(sq2, 2, 64);
        s += __shfl_down(s, 1, 64);  sq2 += __shfl_down(sq2, 1, 64);
        if (part == 0) {
            float mean = s * (1.0f / (float)NBT);
            float var  = sq2 * (1.0f / (float)NBT) - mean * mean;
            float sc = sgamma[o] * rsqrtf(var + 1e-5f);
            scv8[ch] = sc;
            shv8[ch] = sbeta[o] - mean * sc;
        }
    }

    /* load full k-group x1/x2 (32 channels) */
    #pragma unroll
    for (int i = 0; i < 8; i++) {
        int e = tid + i * 256;
        int c = e >> 6, v = e & 63;
        x1k[c][v] = x1[((size_t)b * O_ + k * 32 + c) * V_ + v];
        x2k[c][v] = x2[((size_t)b * O_ + k * 32 + c) * V_ + v];
    }
    __syncthreads();

    /* in-block ada: thread (w = tid>>2, g = tid&3) handles v = g*16..+15 */
    {
        int w = tid >> 2, g = tid & 3;
        float sv[16];
        #pragma unroll
        for (int j = 0; j < 16; j++) sv[j] = 0.f;
        #pragma unroll
        for (int c = 0; c < 32; c++) {
            float x2v = x2k[c][w];
            #pragma unroll
            for (int j = 0; j < 16; j++) sv[j] += x1k[c][g * 16 + j] * x2v;
        }
        float mx = sv[0];
        #pragma unroll
        for (int j = 1; j < 16; j++) mx = fmaxf(mx, sv[j]);
        mx = fmaxf(mx, __shfl_xor(mx, 1, 64));
        mx = fmaxf(mx, __shfl_xor(mx, 2, 64));
        float esum = 0.f;
        #pragma unroll
        for (int j = 0; j < 16; j++) { sv[j] = __expf(sv[j] - mx); esum += sv[j]; }
        esum += __shfl_xor(esum, 1, 64);
        esum += __shfl_xor(esum, 2, 64);
        float rinv = 1.0f / esum;
        #pragma unroll
        for (int j = 0; j < 16; j++) adaS[g * 16 + j][w] = sv[j] * rinv;
    }
    __syncthreads();

    const float* Apk = A_param + (size_t)k * 4096;
    #pragma unroll
    for (int i = 0; i < 4; i++) {
        int e4 = tid + i * 256;          /* float4 index over [v][w] */
        int v = e4 >> 4, w4 = (e4 & 15) * 4;
        float4 ap = *(const float4*)(Apk + (size_t)e4 * 4);
        ComT[w4 + 0][v] = ap.x + beta * adaS[v][w4 + 0];
        ComT[w4 + 1][v] = ap.y + beta * adaS[v][w4 + 1];
        ComT[w4 + 2][v] = ap.z + beta * adaS[v][w4 + 2];
        ComT[w4 + 3][v] = ap.w + beta * adaS[v][w4 + 3];
    }
    __syncthreads();

    short8 bfrag[2][2][4];
    #pragma unroll
    for (int half = 0; half < 2; half++) {
        int cl = wm + half * 4;
        #pragma unroll
        for (int kk = 0; kk < 2; kk++) {
            float x1v[8];
            #pragma unroll
            for (int j = 0; j < 8; j++) x1v[j] = x1k[q * 8 + cl][kk * 32 + qq * 8 + j];
            #pragma unroll
            for (int nt = 0; nt < 4; nt++) {
                int w = nt * 16 + ln;
                float x2v = x2k[q * 8 + cl][w];
                float av[8];
                #pragma unroll
                for (int j = 0; j < 8; j++) {
                    int v = kk * 32 + qq * 8 + j;
                    float d = x1v[j] - x2v;
                    float ax = fabsf(d);
                    float e2 = __expf(-2.f * ax);
                    float th = copysignf((1.f - e2) / (1.f + e2), d);
                    av[j] = ComT[w][v] + alpha * th;
                }
                uint4 bp;
                bp.x = pack2(av[0], av[1]); bp.y = pack2(av[2], av[3]);
                bp.z = pack2(av[4], av[5]); bp.w = pack2(av[6], av[7]);
                bfrag[half][kk][nt] = __builtin_bit_cast(short8, bp);
            }
        }
    }

    int o1a = k * 32 + q * 8 + wm;
    float scv[2] = {scv8[wm], scv8[wm + 4]};
    float shv[2] = {shv8[wm], shv8[wm + 4]};
    const ushort_t* zr[2] = {z + ((size_t)b * O_ + o1a) * TN,
                             z + ((size_t)b * O_ + o1a + 4) * TN};
    size_t obase = ((size_t)(b * 128) * 8 + k) * 2048 + q * 512;

    uint4 zc[2][2];
    #pragma unroll
    for (int half = 0; half < 2; half++)
        #pragma unroll
        for (int kk = 0; kk < 2; kk++)
            zc[half][kk] = *(const uint4*)(zr[half] + (0 * 16 + ln) * 64 + kk * 32 + qq * 8);

    for (int mt = 0; mt < 8; mt++) {
        uint4 zn[2][2];
        if (mt < 7) {
            #pragma unroll
            for (int half = 0; half < 2; half++)
                #pragma unroll
                for (int kk = 0; kk < 2; kk++)
                    zn[half][kk] = *(const uint4*)(zr[half] + ((mt + 1) * 16 + ln) * 64 + kk * 32 + qq * 8);
        }
        f32x4 acc[2][4];
        #pragma unroll
        for (int half = 0; half < 2; half++)
            #pragma unroll
            for (int nt = 0; nt < 4; nt++) acc[half][nt] = (f32x4){0.f, 0.f, 0.f, 0.f};
        #pragma unroll
        for (int half = 0; half < 2; half++) {
            float s = scv[half], h = shv[half];
            #pragma unroll
            for (int kk = 0; kk < 2; kk++) {
                uint4 zv = zc[half][kk];
                float f0 = bf2f_lo(zv.x), f1 = bf2f_hi(zv.x);
                float f2 = bf2f_lo(zv.y), f3 = bf2f_hi(zv.y);
                float f4 = bf2f_lo(zv.z), f5 = bf2f_hi(zv.z);
                float f6 = bf2f_lo(zv.w), f7 = bf2f_hi(zv.w);
                uint4 hp;
                hp.x = pack2(fmaxf(f0 * s + h, 0.f), fmaxf(f1 * s + h, 0.f));
                hp.y = pack2(fmaxf(f2 * s + h, 0.f), fmaxf(f3 * s + h, 0.f));
                hp.z = pack2(fmaxf(f4 * s + h, 0.f), fmaxf(f5 * s + h, 0.f));
                hp.w = pack2(fmaxf(f6 * s + h, 0.f), fmaxf(f7 * s + h, 0.f));
                short8 hf = __builtin_bit_cast(short8, hp);
                #pragma unroll
                for (int nt = 0; nt < 4; nt++)
                    acc[half][nt] = __builtin_amdgcn_mfma_f32_16x16x32_bf16(hf, bfrag[half][kk][nt], acc[half][nt], 0, 0, 0);
            }
        }
        #pragma unroll
        for (int half = 0; half < 2; half++) {
            int cl = wm + half * 4;
            #pragma unroll
            for (int nt = 0; nt < 4; nt++)
                #pragma unroll
                for (int r = 0; r < 4; r++)
                    stg[(qq * 4 + r) * 520 + (nt * 16 + ln) * 8 + cl] = f2bf(acc[half][nt][r]);
        }
        __syncthreads();
        #pragma unroll
        for (int ii = 0; ii < 4; ii++) {
            int u = tid + ii * 256;
            int tl = u >> 6, off = u & 63;
            ((uint4*)(h2img + obase + (size_t)(mt * 16 + tl) * 16384))[off] =
                ((const uint4*)stg)[tl * 65 + off];
        }
        __syncthreads();
        if (mt < 7) {
            #pragma unroll
            for (int half = 0; half < 2; half++)
                #pragma unroll
                for (int kk = 0; kk < 2; kk++)
                    zc[half][kk] = zn[half][kk];
        }
    }
}

/* out = relu(bn(u) + x); head BN finalize folded into prologue (each block's
   channel o = (blockIdx.x>>3)&255 -- the &255 strips the batch index (r7 bug:
   missing mask read gamma/psum OOB). 32-slice reduce is L2-hot. */
__global__ __launch_bounds__(256) void k_final(const ushort_t* __restrict__ ub,
                                               const float* __restrict__ x,
                                               const float* __restrict__ psum,
                                               const float* __restrict__ psumsq,
                                               const float* __restrict__ gamma,
                                               const float* __restrict__ betap,
                                               float* __restrict__ out) {
    __shared__ float scsh[2];
    int tid = threadIdx.x;
    int o = (blockIdx.x >> 3) & 255;
    if (tid < 64) {
        int sl = tid & 31;
        float s  = psum[sl * 256 + o];
        float sq = psumsq[sl * 256 + o];
        #pragma unroll
        for (int off = 1; off <= 16; off <<= 1) {
            s  += __shfl_xor(s,  off, 64);
            sq += __shfl_xor(sq, off, 64);
        }
        if (tid == 0) {
            float mean = s  * (1.0f / (float)NBT);
            float var  = sq * (1.0f / (float)NBT) - mean * mean;
            float sc = gamma[o] * rsqrtf(var + 1e-5f);
            scsh[0] = sc;
            scsh[1] = betap[o] - mean * sc;
        }
    }
    __syncthreads();
    float sc = scsh[0], sh = scsh[1];
    size_t i4 = (size_t)blockIdx.x * 256 + tid;
    uint2 uv = ((const uint2*)ub)[i4];
    float4 xv = ((const float4*)x)[i4];
    float4 r;
    r.x = fmaxf(bf2f_lo(uv.x) * sc + sh + xv.x, 0.f);
    r.y = fmaxf(bf2f_hi(uv.x) * sc + sh + xv.y, 0.f);
    r.z = fmaxf(bf2f_lo(uv.y) * sc + sh + xv.z, 0.f);
    r.w = fmaxf(bf2f_hi(uv.y) * sc + sh + xv.w, 0.f);
    ((float4*)out)[i4] = r;
}

extern "C" void kernel_launch(void* const* d_in, const int* in_sizes, int n_in,
                              void* d_out, int out_size, void* d_ws, size_t ws_size,
                              hipStream_t stream) {
    const float* x          = (const float*)d_in[0];
    const float* A_param    = (const float*)d_in[1];
    const float* alphap     = (const float*)d_in[2];
    const float* betap      = (const float*)d_in[3];
    const float* w1         = (const float*)d_in[4];
    const float* b1         = (const float*)d_in[5];
    const float* w2         = (const float*)d_in[6];
    const float* b2         = (const float*)d_in[7];
    const float* stem_w     = (const float*)d_in[8];
    const float* stem_b     = (const float*)d_in[9];
    const float* stem_gamma = (const float*)d_in[10];
    const float* stem_beta  = (const float*)d_in[11];
    const float* head_w     = (const float*)d_in[12];
    const float* head_b     = (const float*)d_in[13];
    const float* head_gamma = (const float*)d_in[14];
    const float* head_beta  = (const float*)d_in[15];

    float* W      = (float*)d_ws;
    float* tp     = W + OFF_TP;
    float* x1b    = W + OFF_X1;
    float* x2b    = W + OFF_X2;
    float* ssum   = W + OFF_STATS;               /* [NSL][256] */
    float* ssq    = W + OFF_STATS + NSL * 256;
    float* hsum   = W + OFF_STATS + NSL * 512;
    float* hsq    = W + OFF_STATS + NSL * 768;
    float* uout   = (float*)d_out;

    ushort_t* xTimg  = (ushort_t*)d_out;          /* dead before k_final writes d_out */
    ushort_t* wsimg  = (ushort_t*)(W + OFF_WIMG); /* stem+head bf16 images, contiguous */
    ushort_t* zb16   = (ushort_t*)(W + OFF_Z);    /* z bf16; u reuses it after einsum */
    ushort_t* ub16   = zb16;
    ushort_t* h2img  = (ushort_t*)(W + OFF_H2);

    /* zero tp, x1, x2, sliced stats (contiguous) */
    hipMemsetAsync(W, 0, (size_t)(OFF_STATS + NSL * 1024) * sizeof(float), stream);

    k_xpose2<<<dim3(4, 8, 17), 512, 0, stream>>>(x, xTimg, tp, stem_w, head_w, wsimg);
    k_x1x2a<<<dim3(16, 4, 16), 256, 0, stream>>>(tp, w1, b1, w2, b2, x1b, x2b);

    k_gemm<<<dim3(128, 1, 16), 256, 0, stream>>>(xTimg, wsimg, stem_b, zb16, ssum, ssq);

    k_einsum_mfma<<<512, 256, 0, stream>>>(zb16, x1b, x2b, A_param, alphap, betap,
                                           ssum, ssq, stem_gamma, stem_beta, h2img);

    k_gemm<<<dim3(128, 1, 16), 256, 0, stream>>>(h2img, wsimg + 65536, head_b, ub16, hsum, hsq);
    k_final<<<32768, 256, 0, stream>>>(ub16, x, hsum, hsq, head_gamma, head_beta, uout);
}